// Round 9
// baseline (417.597 us; speedup 1.0000x reference)
//
#include <hip/hip_runtime.h>
#include <math.h>

#define Bsz 128
#define Tsz 256
#define Isz 256
#define Hsz 256
#define Lsz 4
#define Ssz 3
#define Mrows (Bsz*Tsz)   // 32768

using f16x8 = __attribute__((ext_vector_type(8))) _Float16;
using f32x4 = __attribute__((ext_vector_type(4))) float;

#define LOG2E 1.44269504f

// ---------------- fp32 -> fp16 convert, 3 segments in one launch ----------------
__global__ __launch_bounds__(256) void f32_to_f16_3(
    const float* __restrict__ s0, _Float16* __restrict__ d0, int n0,
    const float* __restrict__ s1, _Float16* __restrict__ d1, int n1,
    const float* __restrict__ s2, _Float16* __restrict__ d2, int n2)
{
  int idx = blockIdx.x * 256 + threadIdx.x;
  const float* s; _Float16* d;
  if (idx < n0)           { s = s0; d = d0; }
  else if (idx < n0 + n1) { idx -= n0; s = s1; d = d1; }
  else                    { idx -= n0 + n1; if (idx >= n2) return; s = s2; d = d2; }
  const float4 v0 = *(const float4*)(s + (size_t)idx * 8);
  const float4 v1 = *(const float4*)(s + (size_t)idx * 8 + 4);
  _Float16 h[8];
  h[0] = (_Float16)v0.x; h[1] = (_Float16)v0.y;
  h[2] = (_Float16)v0.z; h[3] = (_Float16)v0.w;
  h[4] = (_Float16)v1.x; h[5] = (_Float16)v1.y;
  h[6] = (_Float16)v1.z; h[7] = (_Float16)v1.w;
  *(uint4*)(d + (size_t)idx * 8) = *(uint4*)h;
}

// ---------------- weight-stationary fused GRU-layer GEMM, fp16 MFMA ----------------
// R5-proven inner structure. Tail-packing fix: 256 rows/block (8 chunks),
// grid (128,4,3) = 1536 blocks = EXACTLY 3 residency rounds at 2 blocks/CU
// (vs 768 blocks = 1.5 rounds -> 25% idle tail).
__global__ __launch_bounds__(256, 2) void gemm_gru_f16(
    const _Float16* __restrict__ Abase, size_t a_cur_stride,
    const _Float16* __restrict__ Wbase, size_t w_cur_stride,
    const float* __restrict__ bi_g, size_t bi_stride,
    const float* __restrict__ bh_g, size_t bh_stride,
    _Float16* __restrict__ Hout)
{
  // 3 x 16 KB ring: 32 planes (pk = k0*4+q) x 32 rows x 16B each.
  __shared__ _Float16 AhS[3][8192];

  const int tid  = threadIdx.x;
  const int cu   = blockIdx.z;
  const int n0   = blockIdx.y * 64;
  const int rmb  = blockIdx.x * 256;       // this block's M range: 256 rows

  const _Float16* A = Abase + (size_t)cu * a_cur_stride;
  const _Float16* W = Wbase + (size_t)cu * w_cur_stride;
  const float* bi = bi_g + (size_t)cu * bi_stride;
  const float* bh = bh_g + (size_t)cu * bh_stride;

  const int lane = tid & 63;
  const int wv   = tid >> 6;       // wave id 0..3
  const int q    = lane >> 4;      // k-sub within frag (0..3)
  const int c    = lane & 15;      // row (A) / col (W,D) within frag

  // ---- load stationary W frags: wf[slab][k0], lane(q,c) = W[s*256+ncol][k0*32+q*8..+7]
  const int ncol = n0 + wv * 16 + c;
  f16x8 wf[3][8];
  #pragma unroll
  for (int s = 0; s < 3; s++)
    #pragma unroll
    for (int k0 = 0; k0 < 8; k0++)
      wf[s][k0] = *(const f16x8*)(W + (size_t)(s * 256 + ncol) * 256 + k0 * 32 + q * 8);
  // pin: force wf to live in VGPRs once; defeats rematerialization into the loop
  #pragma unroll
  for (int s = 0; s < 3; s++)
    #pragma unroll
    for (int k0 = 0; k0 < 8; k0++)
      asm volatile("" : "+v"(wf[s][k0]));

  // ---- biases folded into exp2 arguments (per-lane constants)
  const float c0  = -LOG2E * (bi[ncol] + bh[ncol]);
  const float c1  =  LOG2E * (bi[256 + ncol] + bh[256 + ncol]);
  const float c3  = 2.f * LOG2E * bi[512 + ncol];
  const float bhn = bh[512 + ncol];

  f32x4 acc[3][2];

  // ---- stage chunk (32 rows x 256 K) into buf: 16 x 1KB wave-instrs, 4/wave.
  auto stage = [&](int buf, int ch) {
    const int rm = rmb + ch * 32;
    #pragma unroll
    for (int i = 0; i < 4; i++) {
      const int p0 = 8 * wv + 2 * i;                 // base plane (uniform)
      const int pk = p0 + (lane >> 5);               // this lane's plane
      const _Float16* src = A + (size_t)(rm + (lane & 31)) * 256 + pk * 8;
      __builtin_amdgcn_global_load_lds(
          (const __attribute__((address_space(1))) void*)src,
          (__attribute__((address_space(3))) void*)&AhS[buf][p0 * 256],
          16, 0, 0);
    }
  };

  // ---- compute + fused gating epilogue for one chunk (8 outputs/lane)
  auto compute_chunk = [&](int buf, int ch) {
    const int rm = rmb + ch * 32;
    #pragma unroll
    for (int s = 0; s < 3; s++)
      #pragma unroll
      for (int mi = 0; mi < 2; mi++)
        acc[s][mi] = (f32x4)0.f;
    #pragma unroll
    for (int k0 = 0; k0 < 8; k0++) {
      const f16x8 a0 = *(const f16x8*)&AhS[buf][(k0 * 4 + q) * 256 + c * 8];
      const f16x8 a1 = *(const f16x8*)&AhS[buf][(k0 * 4 + q) * 256 + 128 + c * 8];
      #pragma unroll
      for (int s = 0; s < 3; s++) {
        acc[s][0] = __builtin_amdgcn_mfma_f32_16x16x32_f16(a0, wf[s][k0], acc[s][0], 0, 0, 0);
        acc[s][1] = __builtin_amdgcn_mfma_f32_16x16x32_f16(a1, wf[s][k0], acc[s][1], 0, 0, 0);
      }
    }
    #pragma unroll
    for (int mi = 0; mi < 2; mi++) {
      #pragma unroll
      for (int reg = 0; reg < 4; reg++) {
        const float ar = acc[0][mi][reg];
        const float az = acc[1][mi][reg];
        const float an = acc[2][mi][reg];
        const float e0 = __builtin_amdgcn_exp2f(fmaf(-LOG2E, ar, c0));
        const float r  = __builtin_amdgcn_rcpf(1.f + e0);
        const float e1 = __builtin_amdgcn_exp2f(fmaf(LOG2E, az, c1));
        const float tt = fmaf(r, bhn, an);
        const float a2 = fminf(fmaf(2.f * LOG2E, tt, c3), 120.f);
        const float e2 = __builtin_amdgcn_exp2f(a2);
        const float out = (e2 - 1.f) *
            __builtin_amdgcn_rcpf((1.f + e1) * (1.f + e2));
        const size_t row = (size_t)cu * Mrows + rm + mi * 16 + q * 4 + reg;
        Hout[row * 256 + ncol] = (_Float16)out;
      }
    }
  };

  // ---- prologue: 2 chunks in flight, drain chunk 0 (also drains wf/bias loads)
  stage(0, 0);
  stage(1, 1);
  asm volatile("s_waitcnt vmcnt(4)" ::: "memory");
  __builtin_amdgcn_s_barrier();

  // ---- main loop over 8 chunks: {stage(t+2) || compute(t)}, one barrier/chunk.
  // vmcnt(12) = 4 stage + 8 stores in flight -> stage(t+1) drained.
  int bc = 0;
  for (int t = 0; t < 6; ++t) {
    int bs = bc + 2; if (bs >= 3) bs -= 3;
    stage(bs, t + 2);
    compute_chunk(bc, t);
    asm volatile("s_waitcnt vmcnt(12)" ::: "memory");
    __builtin_amdgcn_s_barrier();
    bc = (bc + 1 == 3) ? 0 : bc + 1;
  }
  compute_chunk(bc, 6);                  // bc = 0 = 6%3
  asm volatile("s_waitcnt vmcnt(0)" ::: "memory");
  __builtin_amdgcn_s_barrier();
  compute_chunk(1, 7);                   // 7%3 = 1
}

// ---------------- per-layer dot products (e, p), de-staged ----------------
__global__ __launch_bounds__(256) void ep_tile(
    const _Float16* __restrict__ Hh,
    const float* __restrict__ w_lw, const float* __restrict__ w_sel, int layer,
    float* __restrict__ e, float* __restrict__ p)
{
  __shared__ float wc[7][256];        // 7 KB
  __shared__ float ps[4][64][8];      // 8 KB partials
  const int tid = threadIdx.x;
  const size_t mg0 = (size_t)blockIdx.x * 64;

  #pragma unroll
  for (int j = 0; j < 7; j++)
    wc[j][tid] = (j < 4) ? w_lw[j * 256 + tid] : w_sel[(j - 4) * 512 + tid];
  __syncthreads();

  const int r = tid & 63, pp = tid >> 6;
  const _Float16* hrow = Hh + (mg0 + r) * 256 + pp * 64;
  float acc[7] = {0.f, 0.f, 0.f, 0.f, 0.f, 0.f, 0.f};
  #pragma unroll
  for (int i = 0; i < 8; i++) {
    union { uint4 u; _Float16 h[8]; } hv;
    hv.u = *(const uint4*)(hrow + i * 8);
    float hf[8];
    #pragma unroll
    for (int k = 0; k < 8; k++) hf[k] = (float)hv.h[k];
    #pragma unroll
    for (int j = 0; j < 7; j++) {
      const float4 w0 = *(const float4*)&wc[j][pp * 64 + i * 8];
      const float4 w1 = *(const float4*)&wc[j][pp * 64 + i * 8 + 4];
      acc[j] += hf[0] * w0.x + hf[1] * w0.y + hf[2] * w0.z + hf[3] * w0.w
              + hf[4] * w1.x + hf[5] * w1.y + hf[6] * w1.z + hf[7] * w1.w;
    }
  }
  #pragma unroll
  for (int j = 0; j < 7; j++) ps[pp][r][j] = acc[j];
  __syncthreads();

  if (tid < 64) {
    float d[7];
    #pragma unroll
    for (int j = 0; j < 7; j++)
      d[j] = ps[0][tid][j] + ps[1][tid][j] + ps[2][tid][j] + ps[3][tid][j];
    const size_t mg = mg0 + tid;
    const int cc = (int)(mg >> 15);          // / Mrows
    const int m  = (int)(mg & 32767);
    const int b = m >> 8, t = m & 255;
    const size_t base = ((size_t)cc * Tsz + t) * Bsz + b;
    #pragma unroll
    for (int j = 0; j < 4; j++) e[base * 16 + layer * 4 + j] = d[j];
    #pragma unroll
    for (int j = 0; j < 3; j++) p[base * 12 + layer * 3 + j] = d[4 + j];
  }
}

// ---------------- softmax-attention + batch-reduced selector scores ----------------
__global__ __launch_bounds__(128) void attn_finish(
    const float* __restrict__ e, const float* __restrict__ p,
    const float* __restrict__ hidden, const float* __restrict__ b_lw,
    float* __restrict__ score_h)
{
  const int t = blockIdx.x, cc = blockIdx.y;
  const int b = threadIdx.x;
  const float* eb = e + ((size_t)(cc * Tsz + t) * Bsz + b) * 16;
  const float* pb = p + ((size_t)(cc * Tsz + t) * Bsz + b) * 12;
  const float* hb = hidden + b * 16;
  const float bl0 = b_lw[0], bl1 = b_lw[1], bl2 = b_lw[2], bl3 = b_lw[3];
  float attn[4];
  #pragma unroll
  for (int i = 0; i < 4; i++) {
    attn[i] = hb[i * 4 + 0] * (eb[i * 4 + 0] + bl0)
            + hb[i * 4 + 1] * (eb[i * 4 + 1] + bl1)
            + hb[i * 4 + 2] * (eb[i * 4 + 2] + bl2)
            + hb[i * 4 + 3] * (eb[i * 4 + 3] + bl3);
  }
  const float mx = fmaxf(fmaxf(attn[0], attn[1]), fmaxf(attn[2], attn[3]));
  float ex[4], sum = 0.f;
  #pragma unroll
  for (int i = 0; i < 4; i++) { ex[i] = expf(attn[i] - mx); sum += ex[i]; }
  const float inv = 1.f / sum;
  float sc[3];
  #pragma unroll
  for (int s = 0; s < 3; s++) {
    float v = 0.f;
    #pragma unroll
    for (int i = 0; i < 4; i++) v += ex[i] * pb[i * 3 + s];
    sc[s] = v * inv;
  }
  #pragma unroll
  for (int off = 32; off; off >>= 1)
    #pragma unroll
    for (int s = 0; s < 3; s++) sc[s] += __shfl_xor(sc[s], off);
  __shared__ float red[2][3];
  const int wv = threadIdx.x >> 6, ln = threadIdx.x & 63;
  if (ln == 0) { red[wv][0] = sc[0]; red[wv][1] = sc[1]; red[wv][2] = sc[2]; }
  __syncthreads();
  if (threadIdx.x == 0) {
    #pragma unroll
    for (int s = 0; s < 3; s++)
      score_h[((size_t)cc * Tsz + t) * 3 + s] = red[0][s] + red[1][s];
  }
}

// ---------------- xs[t,s] ----------------
__global__ __launch_bounds__(256) void xs_kernel(
    const float* __restrict__ x, const float* __restrict__ w_sel,
    const float* __restrict__ b_sel, float* __restrict__ xs)
{
  const int t = blockIdx.x, k = threadIdx.x;
  float s = 0.f;
  for (int b = 0; b < Bsz; b++) s += x[((size_t)b * Tsz + t) * Isz + k];
  float pr[3];
  #pragma unroll
  for (int qq = 0; qq < 3; qq++) pr[qq] = s * w_sel[qq * (Hsz + Isz) + Hsz + k];
  #pragma unroll
  for (int off = 32; off; off >>= 1)
    #pragma unroll
    for (int qq = 0; qq < 3; qq++) pr[qq] += __shfl_xor(pr[qq], off);
  __shared__ float red[4][3];
  const int wv = k >> 6, ln = k & 63;
  if (ln == 0) { red[wv][0] = pr[0]; red[wv][1] = pr[1]; red[wv][2] = pr[2]; }
  __syncthreads();
  if (k == 0) {
    #pragma unroll
    for (int qq = 0; qq < 3; qq++)
      xs[t * 3 + qq] = red[0][qq] + red[1][qq] + red[2][qq] + red[3][qq]
                      + (float)Bsz * b_sel[qq];
  }
}

// ---------------- selector chain via parallel map-composition scan ----------------
// cur[t] = f[t](cur[t-1]), f[t]: {0,1,2}->{0,1,2}. Composition is associative
// -> Hillis-Steele inclusive scan over 6-bit-packed maps (8 stages) replaces
// the 255-step dependent-latency serial chain.
__global__ __launch_bounds__(256) void select_kernel(
    const float* __restrict__ score_h, const float* __restrict__ xs,
    int* __restrict__ cur)
{
  __shared__ unsigned S[Tsz];
  const int t = threadIdx.x;

  unsigned m = 0x24;                     // identity map: 0->0,1->1,2->2
  if (t >= 1) {
    m = 0;
    const float* xr = xs + t * 3;
    #pragma unroll
    for (int cc = 0; cc < 3; cc++) {
      const float* sh = score_h + ((size_t)cc * Tsz + (t - 1)) * 3;
      const float v0 = sh[0] + xr[0];
      const float v1 = sh[1] + xr[1];
      const float v2 = sh[2] + xr[2];
      unsigned best = 0; float bv = v0;
      if (v1 > bv) { bv = v1; best = 1; }
      if (v2 > bv) { bv = v2; best = 2; }
      m |= best << (2 * cc);
    }
  }
  S[t] = m;
  __syncthreads();

  #pragma unroll
  for (int d = 1; d < Tsz; d <<= 1) {
    const unsigned prev = (t >= d) ? S[t - d] : 0x24u;  // identity pad
    const unsigned self = S[t];
    __syncthreads();
    unsigned comp = 0;
    #pragma unroll
    for (int x = 0; x < 3; x++) {
      const unsigned y = (prev >> (2 * x)) & 3u;
      const unsigned z = (self >> (2 * y)) & 3u;
      comp |= z << (2 * x);
    }
    S[t] = comp;
    __syncthreads();
  }
  cur[t] = (int)(S[t] & 3u);             // composite applied to cur[0]=0
}

// ---------------- gather outputs (fp16 h -> fp32 out) ----------------
__global__ __launch_bounds__(256) void gather_out(
    const _Float16* __restrict__ Hh, const int* __restrict__ cur,
    float* __restrict__ out)
{
  const size_t idx = ((size_t)blockIdx.x * 256 + threadIdx.x) * 4;
  const size_t BTH = (size_t)Bsz * Tsz * Hsz;
  int b, t, h;
  if (idx < BTH) {
    b = (int)(idx >> 16);
    const int rem = (int)(idx & 65535);
    t = rem >> 8; h = rem & 255;
  } else {
    const size_t r2 = idx - BTH;
    b = (int)(r2 >> 8); h = (int)(r2 & 255); t = Tsz - 1;
  }
  const int cc = cur[t];
  const size_t g = (((size_t)cc * Mrows + (size_t)b * Tsz + t) * Hsz + h);
  union { ushort4 u; _Float16 hv[4]; } cv;
  cv.u = *(const ushort4*)(Hh + g);
  float4 v;
  v.x = (float)cv.hv[0]; v.y = (float)cv.hv[1];
  v.z = (float)cv.hv[2]; v.w = (float)cv.hv[3];
  *(float4*)(out + idx) = v;
}

extern "C" void kernel_launch(void* const* d_in, const int* in_sizes, int n_in,
                              void* d_out, int out_size, void* d_ws, size_t ws_size,
                              hipStream_t stream) {
  const float* x      = (const float*)d_in[0];
  const float* hidden = (const float*)d_in[1];
  const float* w_ih0  = (const float*)d_in[2];
  const float* b_ih0  = (const float*)d_in[3];
  const float* b_hh0  = (const float*)d_in[4];
  const float* w_ih   = (const float*)d_in[5];
  const float* b_ih   = (const float*)d_in[6];
  const float* b_hh   = (const float*)d_in[7];
  const float* w_lw   = (const float*)d_in[8];
  const float* b_lw   = (const float*)d_in[9];
  const float* w_sel  = (const float*)d_in[10];
  const float* b_sel  = (const float*)d_in[11];
  float* out = (float*)d_out;

  char* w = (char*)d_ws;
  const size_t HN = (size_t)3 * Mrows * 256;       // 25.2M
  const size_t XN = (size_t)Bsz * Tsz * Isz;       // 8.39M
  const size_t W0N = (size_t)3 * 768 * 256;        // 589824
  const size_t WLN = (size_t)3 * 3 * 768 * 256;    // 1769472
  _Float16* HA  = (_Float16*)w; w += HN * 2;
  _Float16* HB  = (_Float16*)w; w += HN * 2;
  _Float16* xh  = (_Float16*)w; w += XN * 2;
  _Float16* Wh0 = (_Float16*)w; w += W0N * 2;
  _Float16* WhL = (_Float16*)w; w += WLN * 2;
  float* e       = (float*)w; w += (size_t)3 * Tsz * Bsz * 16 * 4;
  float* p       = (float*)w; w += (size_t)3 * Tsz * Bsz * 12 * 4;
  float* score_h = (float*)w; w += (size_t)3 * Tsz * 3 * 4;
  float* xsb     = (float*)w; w += (size_t)Tsz * 3 * 4;
  int*   curb    = (int*)w;   w += (size_t)Tsz * 4;

  // fp32 -> fp16 conversions (one launch, 3 segments)
  f32_to_f16_3<<<5248, 256, 0, stream>>>(
      x, xh, (int)(XN / 8),
      w_ih0, Wh0, (int)(W0N / 8),
      w_ih, WhL, (int)(WLN / 8));

  // weight-stationary GEMM grid: (mseg, n-tile, cur) = 1536 blocks (3 rounds)
  dim3 ggrid(128, 4, 3);

  // layer 0: A = xh (shared across cur)
  gemm_gru_f16<<<ggrid, 256, 0, stream>>>(
      xh, (size_t)0, Wh0, (size_t)768 * 256,
      b_ih0, (size_t)768, b_hh0, (size_t)768, HA);
  ep_tile<<<(3 * Mrows) / 64, 256, 0, stream>>>(HA, w_lw, w_sel, 0, e, p);

  const size_t wcur = (size_t)3 * 768 * 256;
  const size_t bst  = (size_t)3 * 768;
  _Float16* ping = HA; _Float16* pong = HB;
  for (int l = 1; l < 4; l++) {
    gemm_gru_f16<<<ggrid, 256, 0, stream>>>(
        ping, (size_t)Mrows * 256,
        WhL + (size_t)(l - 1) * 768 * 256, wcur,
        b_ih + (size_t)(l - 1) * 768, bst,
        b_hh + (size_t)(l - 1) * 768, bst, pong);
    ep_tile<<<(3 * Mrows) / 64, 256, 0, stream>>>(pong, w_lw, w_sel, l, e, p);
    _Float16* t1 = ping; ping = pong; pong = t1;
  }

  attn_finish<<<dim3(Tsz, 3), 128, 0, stream>>>(e, p, hidden, b_lw, score_h);
  xs_kernel<<<Tsz, 256, 0, stream>>>(x, w_sel, b_sel, xsb);
  select_kernel<<<1, 256, 0, stream>>>(score_h, xsb, curb);
  gather_out<<<8224, 256, 0, stream>>>(ping, curb, out);
}

// Round 11
// 412.701 us; speedup vs baseline: 1.0119x; 1.0119x over previous
//
#include <hip/hip_runtime.h>
#include <math.h>

#define Bsz 128
#define Tsz 256
#define Isz 256
#define Hsz 256
#define Lsz 4
#define Ssz 3
#define Mrows (Bsz*Tsz)   // 32768

using f16x8 = __attribute__((ext_vector_type(8))) _Float16;
using f32x4 = __attribute__((ext_vector_type(4))) float;

#define LOG2E 1.44269504f

// ---------------- fp32 -> fp16 convert, 3 segments in one launch ----------------
__global__ __launch_bounds__(256) void f32_to_f16_3(
    const float* __restrict__ s0, _Float16* __restrict__ d0, int n0,
    const float* __restrict__ s1, _Float16* __restrict__ d1, int n1,
    const float* __restrict__ s2, _Float16* __restrict__ d2, int n2)
{
  int idx = blockIdx.x * 256 + threadIdx.x;
  const float* s; _Float16* d;
  if (idx < n0)           { s = s0; d = d0; }
  else if (idx < n0 + n1) { idx -= n0; s = s1; d = d1; }
  else                    { idx -= n0 + n1; if (idx >= n2) return; s = s2; d = d2; }
  const float4 v0 = *(const float4*)(s + (size_t)idx * 8);
  const float4 v1 = *(const float4*)(s + (size_t)idx * 8 + 4);
  _Float16 h[8];
  h[0] = (_Float16)v0.x; h[1] = (_Float16)v0.y;
  h[2] = (_Float16)v0.z; h[3] = (_Float16)v0.w;
  h[4] = (_Float16)v1.x; h[5] = (_Float16)v1.y;
  h[6] = (_Float16)v1.z; h[7] = (_Float16)v1.w;
  *(uint4*)(d + (size_t)idx * 8) = *(uint4*)h;
}

// ---------------- weight-stationary fused GRU-layer GEMM, fp16 MFMA ----------------
// R7-proven grid/ring (64 msegs x 512 rows, 16 chunks, 3-buf LDS ring).
// Deferred epilogue: chunk t's gating epilogue runs AFTER the barrier,
// interleaved with chunk t+1's ds_reads/MFMAs (double accumulator accA/accB).
// vmcnt ledger (FIXED from prior round): prologue drains vmcnt(0) so chunk 1
// is ready without relying on iter-0's count (iter 0 defers its epilogue and
// issues only 4 loads, making vmcnt(12) a no-op there). For t>=1, the 12
// newest at the wait = stage(t+2)x4 + epi(t-1)x8 -> stage(t+1) drained.
__global__ __launch_bounds__(256, 2) void gemm_gru_f16(
    const _Float16* __restrict__ Abase, size_t a_cur_stride,
    const _Float16* __restrict__ Wbase, size_t w_cur_stride,
    const float* __restrict__ bi_g, size_t bi_stride,
    const float* __restrict__ bh_g, size_t bh_stride,
    _Float16* __restrict__ Hout)
{
  // 3 x 16 KB ring: 32 planes (pk = k0*4+q) x 32 rows x 16B each.
  __shared__ _Float16 AhS[3][8192];

  const int tid  = threadIdx.x;
  const int cu   = blockIdx.z;
  const int n0   = blockIdx.y * 64;
  const int rmb  = blockIdx.x * 512;       // this block's M range: 512 rows

  const _Float16* A = Abase + (size_t)cu * a_cur_stride;
  const _Float16* W = Wbase + (size_t)cu * w_cur_stride;
  const float* bi = bi_g + (size_t)cu * bi_stride;
  const float* bh = bh_g + (size_t)cu * bh_stride;

  const int lane = tid & 63;
  const int wv   = tid >> 6;       // wave id 0..3
  const int q    = lane >> 4;      // k-sub within frag (0..3)
  const int c    = lane & 15;      // row (A) / col (W,D) within frag

  // ---- load stationary W frags: wf[slab][k0], lane(q,c) = W[s*256+ncol][k0*32+q*8..+7]
  const int ncol = n0 + wv * 16 + c;
  f16x8 wf[3][8];
  #pragma unroll
  for (int s = 0; s < 3; s++)
    #pragma unroll
    for (int k0 = 0; k0 < 8; k0++)
      wf[s][k0] = *(const f16x8*)(W + (size_t)(s * 256 + ncol) * 256 + k0 * 32 + q * 8);
  // pin: force wf to live in VGPRs once; defeats rematerialization into the loop
  #pragma unroll
  for (int s = 0; s < 3; s++)
    #pragma unroll
    for (int k0 = 0; k0 < 8; k0++)
      asm volatile("" : "+v"(wf[s][k0]));

  // ---- biases folded into exp2 arguments (per-lane constants)
  const float c0  = -LOG2E * (bi[ncol] + bh[ncol]);
  const float c1  =  LOG2E * (bi[256 + ncol] + bh[256 + ncol]);
  const float c3  = 2.f * LOG2E * bi[512 + ncol];
  const float bhn = bh[512 + ncol];

  f32x4 accA[3][2], accB[3][2];

  // ---- stage chunk (32 rows x 256 K) into buf: 16 x 1KB wave-instrs, 4/wave.
  auto stage = [&](int buf, int ch) {
    const int rm = rmb + ch * 32;
    #pragma unroll
    for (int i = 0; i < 4; i++) {
      const int p0 = 8 * wv + 2 * i;                 // base plane (uniform)
      const int pk = p0 + (lane >> 5);               // this lane's plane
      const _Float16* src = A + (size_t)(rm + (lane & 31)) * 256 + pk * 8;
      __builtin_amdgcn_global_load_lds(
          (const __attribute__((address_space(1))) void*)src,
          (__attribute__((address_space(3))) void*)&AhS[buf][p0 * 256],
          16, 0, 0);
    }
  };

  // ---- MFMA-only for one chunk into the given accumulator set
  auto mfma_chunk = [&](f32x4 (&acc)[3][2], int buf) {
    #pragma unroll
    for (int s = 0; s < 3; s++)
      #pragma unroll
      for (int mi = 0; mi < 2; mi++)
        acc[s][mi] = (f32x4)0.f;
    #pragma unroll
    for (int k0 = 0; k0 < 8; k0++) {
      const f16x8 a0 = *(const f16x8*)&AhS[buf][(k0 * 4 + q) * 256 + c * 8];
      const f16x8 a1 = *(const f16x8*)&AhS[buf][(k0 * 4 + q) * 256 + 128 + c * 8];
      #pragma unroll
      for (int s = 0; s < 3; s++) {
        acc[s][0] = __builtin_amdgcn_mfma_f32_16x16x32_f16(a0, wf[s][k0], acc[s][0], 0, 0, 0);
        acc[s][1] = __builtin_amdgcn_mfma_f32_16x16x32_f16(a1, wf[s][k0], acc[s][1], 0, 0, 0);
      }
    }
  };

  // ---- gating epilogue for one chunk from the given accumulator set
  auto epi_chunk = [&](f32x4 (&acc)[3][2], int ch) {
    const int rm = rmb + ch * 32;
    #pragma unroll
    for (int mi = 0; mi < 2; mi++) {
      #pragma unroll
      for (int reg = 0; reg < 4; reg++) {
        const float ar = acc[0][mi][reg];
        const float az = acc[1][mi][reg];
        const float an = acc[2][mi][reg];
        const float e0 = __builtin_amdgcn_exp2f(fmaf(-LOG2E, ar, c0));
        const float r  = __builtin_amdgcn_rcpf(1.f + e0);
        const float e1 = __builtin_amdgcn_exp2f(fmaf(LOG2E, az, c1));
        const float tt = fmaf(r, bhn, an);
        const float a2 = fminf(fmaf(2.f * LOG2E, tt, c3), 120.f);
        const float e2 = __builtin_amdgcn_exp2f(a2);
        const float out = (e2 - 1.f) *
            __builtin_amdgcn_rcpf((1.f + e1) * (1.f + e2));
        const size_t row = (size_t)cu * Mrows + rm + mi * 16 + q * 4 + reg;
        Hout[row * 256 + ncol] = (_Float16)out;
      }
    }
  };

  // ---- prologue: 2 chunks in flight, FULL drain (chunks 0 AND 1 ready).
  // Required: iter 0 defers its epilogue (only 4 loads issued), so its
  // vmcnt(12) cannot drain stage(1).
  stage(0, 0);
  stage(1, 1);
  asm volatile("s_waitcnt vmcnt(0)" ::: "memory");
  __builtin_amdgcn_s_barrier();

  // ---- main loop: 7 pairs covering iterations t = 0..13.
  // iter t: stage(t+2) || MFMA(t) || epilogue(t-1)  [one barrier region]
  for (int tt = 0; tt < 7; ++tt) {
    const int t0 = 2 * tt;                 // even iter -> accA
    {
      stage((t0 + 2) % 3, t0 + 2);
      mfma_chunk(accA, t0 % 3);
      if (tt > 0) epi_chunk(accB, t0 - 1);
      asm volatile("s_waitcnt vmcnt(12)" ::: "memory");
      __builtin_amdgcn_s_barrier();
    }
    {
      const int t1 = t0 + 1;               // odd iter -> accB
      stage((t1 + 2) % 3, t1 + 2);
      mfma_chunk(accB, t1 % 3);
      epi_chunk(accA, t0);
      asm volatile("s_waitcnt vmcnt(12)" ::: "memory");
      __builtin_amdgcn_s_barrier();
    }
  }
  // ---- tail: chunks 14, 15 (both staged; 14 drained by iter-13 wait+barrier)
  mfma_chunk(accA, 2);                     // chunk 14, buf 14%3 = 2
  epi_chunk(accB, 13);
  asm volatile("s_waitcnt vmcnt(0)" ::: "memory");
  __builtin_amdgcn_s_barrier();
  mfma_chunk(accB, 0);                     // chunk 15, buf 15%3 = 0
  epi_chunk(accA, 14);
  epi_chunk(accB, 15);
}

// ---------------- per-layer dot products (e, p), de-staged ----------------
__global__ __launch_bounds__(256) void ep_tile(
    const _Float16* __restrict__ Hh,
    const float* __restrict__ w_lw, const float* __restrict__ w_sel, int layer,
    float* __restrict__ e, float* __restrict__ p)
{
  __shared__ float wc[7][256];        // 7 KB
  __shared__ float ps[4][64][8];      // 8 KB partials
  const int tid = threadIdx.x;
  const size_t mg0 = (size_t)blockIdx.x * 64;

  #pragma unroll
  for (int j = 0; j < 7; j++)
    wc[j][tid] = (j < 4) ? w_lw[j * 256 + tid] : w_sel[(j - 4) * 512 + tid];
  __syncthreads();

  const int r = tid & 63, pp = tid >> 6;
  const _Float16* hrow = Hh + (mg0 + r) * 256 + pp * 64;
  float acc[7] = {0.f, 0.f, 0.f, 0.f, 0.f, 0.f, 0.f};
  #pragma unroll
  for (int i = 0; i < 8; i++) {
    union { uint4 u; _Float16 h[8]; } hv;
    hv.u = *(const uint4*)(hrow + i * 8);
    float hf[8];
    #pragma unroll
    for (int k = 0; k < 8; k++) hf[k] = (float)hv.h[k];
    #pragma unroll
    for (int j = 0; j < 7; j++) {
      const float4 w0 = *(const float4*)&wc[j][pp * 64 + i * 8];
      const float4 w1 = *(const float4*)&wc[j][pp * 64 + i * 8 + 4];
      acc[j] += hf[0] * w0.x + hf[1] * w0.y + hf[2] * w0.z + hf[3] * w0.w
              + hf[4] * w1.x + hf[5] * w1.y + hf[6] * w1.z + hf[7] * w1.w;
    }
  }
  #pragma unroll
  for (int j = 0; j < 7; j++) ps[pp][r][j] = acc[j];
  __syncthreads();

  if (tid < 64) {
    float d[7];
    #pragma unroll
    for (int j = 0; j < 7; j++)
      d[j] = ps[0][tid][j] + ps[1][tid][j] + ps[2][tid][j] + ps[3][tid][j];
    const size_t mg = mg0 + tid;
    const int cc = (int)(mg >> 15);          // / Mrows
    const int m  = (int)(mg & 32767);
    const int b = m >> 8, t = m & 255;
    const size_t base = ((size_t)cc * Tsz + t) * Bsz + b;
    #pragma unroll
    for (int j = 0; j < 4; j++) e[base * 16 + layer * 4 + j] = d[j];
    #pragma unroll
    for (int j = 0; j < 3; j++) p[base * 12 + layer * 3 + j] = d[4 + j];
  }
}

// ---------------- fused: softmax-attention scores (y<3) + xs (y==3) ----------------
__global__ __launch_bounds__(128) void attn_xs(
    const float* __restrict__ e, const float* __restrict__ p,
    const float* __restrict__ hidden, const float* __restrict__ b_lw,
    const float* __restrict__ x, const float* __restrict__ w_sel,
    const float* __restrict__ b_sel,
    float* __restrict__ score_h, float* __restrict__ xs)
{
  __shared__ float red[2][3];
  const int t = blockIdx.x;
  const int wv = threadIdx.x >> 6, ln = threadIdx.x & 63;

  if (blockIdx.y < 3) {
    const int cc = blockIdx.y;
    const int b = threadIdx.x;
    const float* eb = e + ((size_t)(cc * Tsz + t) * Bsz + b) * 16;
    const float* pb = p + ((size_t)(cc * Tsz + t) * Bsz + b) * 12;
    const float* hb = hidden + b * 16;
    const float bl0 = b_lw[0], bl1 = b_lw[1], bl2 = b_lw[2], bl3 = b_lw[3];
    float attn[4];
    #pragma unroll
    for (int i = 0; i < 4; i++) {
      attn[i] = hb[i * 4 + 0] * (eb[i * 4 + 0] + bl0)
              + hb[i * 4 + 1] * (eb[i * 4 + 1] + bl1)
              + hb[i * 4 + 2] * (eb[i * 4 + 2] + bl2)
              + hb[i * 4 + 3] * (eb[i * 4 + 3] + bl3);
    }
    const float mx = fmaxf(fmaxf(attn[0], attn[1]), fmaxf(attn[2], attn[3]));
    float ex[4], sum = 0.f;
    #pragma unroll
    for (int i = 0; i < 4; i++) { ex[i] = expf(attn[i] - mx); sum += ex[i]; }
    const float inv = 1.f / sum;
    float sc[3];
    #pragma unroll
    for (int s = 0; s < 3; s++) {
      float v = 0.f;
      #pragma unroll
      for (int i = 0; i < 4; i++) v += ex[i] * pb[i * 3 + s];
      sc[s] = v * inv;
    }
    #pragma unroll
    for (int off = 32; off; off >>= 1)
      #pragma unroll
      for (int s = 0; s < 3; s++) sc[s] += __shfl_xor(sc[s], off);
    if (ln == 0) { red[wv][0] = sc[0]; red[wv][1] = sc[1]; red[wv][2] = sc[2]; }
    __syncthreads();
    if (threadIdx.x == 0) {
      #pragma unroll
      for (int s = 0; s < 3; s++)
        score_h[((size_t)cc * Tsz + t) * 3 + s] = red[0][s] + red[1][s];
    }
  } else {
    const int k = threadIdx.x;               // handles k and k+128
    float s0 = 0.f, s1 = 0.f;
    for (int b = 0; b < Bsz; b++) {
      const float* xb = x + ((size_t)b * Tsz + t) * Isz;
      s0 += xb[k]; s1 += xb[k + 128];
    }
    float pr[3];
    #pragma unroll
    for (int qq = 0; qq < 3; qq++)
      pr[qq] = s0 * w_sel[qq * (Hsz + Isz) + Hsz + k]
             + s1 * w_sel[qq * (Hsz + Isz) + Hsz + k + 128];
    #pragma unroll
    for (int off = 32; off; off >>= 1)
      #pragma unroll
      for (int qq = 0; qq < 3; qq++) pr[qq] += __shfl_xor(pr[qq], off);
    if (ln == 0) { red[wv][0] = pr[0]; red[wv][1] = pr[1]; red[wv][2] = pr[2]; }
    __syncthreads();
    if (threadIdx.x == 0) {
      #pragma unroll
      for (int qq = 0; qq < 3; qq++)
        xs[t * 3 + qq] = red[0][qq] + red[1][qq] + (float)Bsz * b_sel[qq];
    }
  }
}

// ---------------- selector chain via parallel map-composition scan ----------------
__global__ __launch_bounds__(256) void select_kernel(
    const float* __restrict__ score_h, const float* __restrict__ xs,
    int* __restrict__ cur)
{
  __shared__ unsigned S[Tsz];
  const int t = threadIdx.x;

  unsigned m = 0x24;                     // identity map: 0->0,1->1,2->2
  if (t >= 1) {
    m = 0;
    const float* xr = xs + t * 3;
    #pragma unroll
    for (int cc = 0; cc < 3; cc++) {
      const float* sh = score_h + ((size_t)cc * Tsz + (t - 1)) * 3;
      const float v0 = sh[0] + xr[0];
      const float v1 = sh[1] + xr[1];
      const float v2 = sh[2] + xr[2];
      unsigned best = 0; float bv = v0;
      if (v1 > bv) { bv = v1; best = 1; }
      if (v2 > bv) { bv = v2; best = 2; }
      m |= best << (2 * cc);
    }
  }
  S[t] = m;
  __syncthreads();

  #pragma unroll
  for (int d = 1; d < Tsz; d <<= 1) {
    const unsigned prev = (t >= d) ? S[t - d] : 0x24u;  // identity pad
    const unsigned self = S[t];
    __syncthreads();
    unsigned comp = 0;
    #pragma unroll
    for (int xx = 0; xx < 3; xx++) {
      const unsigned y = (prev >> (2 * xx)) & 3u;
      const unsigned z = (self >> (2 * y)) & 3u;
      comp |= z << (2 * xx);
    }
    S[t] = comp;
    __syncthreads();
  }
  cur[t] = (int)(S[t] & 3u);             // composite applied to cur[0]=0
}

// ---------------- gather outputs (fp16 h -> fp32 out) ----------------
__global__ __launch_bounds__(256) void gather_out(
    const _Float16* __restrict__ Hh, const int* __restrict__ cur,
    float* __restrict__ out)
{
  const size_t idx = ((size_t)blockIdx.x * 256 + threadIdx.x) * 4;
  const size_t BTH = (size_t)Bsz * Tsz * Hsz;
  int b, t, h;
  if (idx < BTH) {
    b = (int)(idx >> 16);
    const int rem = (int)(idx & 65535);
    t = rem >> 8; h = rem & 255;
  } else {
    const size_t r2 = idx - BTH;
    b = (int)(r2 >> 8); h = (int)(r2 & 255); t = Tsz - 1;
  }
  const int cc = cur[t];
  const size_t g = (((size_t)cc * Mrows + (size_t)b * Tsz + t) * Hsz + h);
  union { ushort4 u; _Float16 hv[4]; } cv;
  cv.u = *(const ushort4*)(Hh + g);
  float4 v;
  v.x = (float)cv.hv[0]; v.y = (float)cv.hv[1];
  v.z = (float)cv.hv[2]; v.w = (float)cv.hv[3];
  *(float4*)(out + idx) = v;
}

extern "C" void kernel_launch(void* const* d_in, const int* in_sizes, int n_in,
                              void* d_out, int out_size, void* d_ws, size_t ws_size,
                              hipStream_t stream) {
  const float* x      = (const float*)d_in[0];
  const float* hidden = (const float*)d_in[1];
  const float* w_ih0  = (const float*)d_in[2];
  const float* b_ih0  = (const float*)d_in[3];
  const float* b_hh0  = (const float*)d_in[4];
  const float* w_ih   = (const float*)d_in[5];
  const float* b_ih   = (const float*)d_in[6];
  const float* b_hh   = (const float*)d_in[7];
  const float* w_lw   = (const float*)d_in[8];
  const float* b_lw   = (const float*)d_in[9];
  const float* w_sel  = (const float*)d_in[10];
  const float* b_sel  = (const float*)d_in[11];
  float* out = (float*)d_out;

  char* w = (char*)d_ws;
  const size_t HN = (size_t)3 * Mrows * 256;       // 25.2M
  const size_t XN = (size_t)Bsz * Tsz * Isz;       // 8.39M
  const size_t W0N = (size_t)3 * 768 * 256;        // 589824
  const size_t WLN = (size_t)3 * 3 * 768 * 256;    // 1769472
  _Float16* HA  = (_Float16*)w; w += HN * 2;
  _Float16* HB  = (_Float16*)w; w += HN * 2;
  _Float16* xh  = (_Float16*)w; w += XN * 2;
  _Float16* Wh0 = (_Float16*)w; w += W0N * 2;
  _Float16* WhL = (_Float16*)w; w += WLN * 2;
  float* e       = (float*)w; w += (size_t)3 * Tsz * Bsz * 16 * 4;
  float* p       = (float*)w; w += (size_t)3 * Tsz * Bsz * 12 * 4;
  float* score_h = (float*)w; w += (size_t)3 * Tsz * 3 * 4;
  float* xsb     = (float*)w; w += (size_t)Tsz * 3 * 4;
  int*   curb    = (int*)w;   w += (size_t)Tsz * 4;

  // fp32 -> fp16 conversions (one launch, 3 segments)
  f32_to_f16_3<<<5248, 256, 0, stream>>>(
      x, xh, (int)(XN / 8),
      w_ih0, Wh0, (int)(W0N / 8),
      w_ih, WhL, (int)(WLN / 8));

  // weight-stationary GEMM grid: (mseg, n-tile, cur) — R7-proven 768 blocks
  dim3 ggrid(64, 4, 3);

  // layer 0: A = xh (shared across cur)
  gemm_gru_f16<<<ggrid, 256, 0, stream>>>(
      xh, (size_t)0, Wh0, (size_t)768 * 256,
      b_ih0, (size_t)768, b_hh0, (size_t)768, HA);
  ep_tile<<<(3 * Mrows) / 64, 256, 0, stream>>>(HA, w_lw, w_sel, 0, e, p);

  const size_t wcur = (size_t)3 * 768 * 256;
  const size_t bst  = (size_t)3 * 768;
  _Float16* ping = HA; _Float16* pong = HB;
  for (int l = 1; l < 4; l++) {
    gemm_gru_f16<<<ggrid, 256, 0, stream>>>(
        ping, (size_t)Mrows * 256,
        WhL + (size_t)(l - 1) * 768 * 256, wcur,
        b_ih + (size_t)(l - 1) * 768, bst,
        b_hh + (size_t)(l - 1) * 768, bst, pong);
    ep_tile<<<(3 * Mrows) / 64, 256, 0, stream>>>(pong, w_lw, w_sel, l, e, p);
    _Float16* t1 = ping; ping = pong; pong = t1;
  }

  attn_xs<<<dim3(Tsz, 4), 128, 0, stream>>>(
      e, p, hidden, b_lw, x, w_sel, b_sel, score_h, xsb);
  select_kernel<<<1, 256, 0, stream>>>(score_h, xsb, curb);
  gather_out<<<8224, 256, 0, stream>>>(ping, curb, out);
}

// Round 13
// 402.845 us; speedup vs baseline: 1.0366x; 1.0245x over previous
//
#include <hip/hip_runtime.h>
#include <math.h>

#define Bsz 128
#define Tsz 256
#define Isz 256
#define Hsz 256
#define Lsz 4
#define Ssz 3
#define Mrows (Bsz*Tsz)   // 32768

using f16x8 = __attribute__((ext_vector_type(8))) _Float16;
using f32x4 = __attribute__((ext_vector_type(4))) float;

#define LOG2E 1.44269504f

// ---------------- fp32 -> fp16 convert, 3 segments in one launch ----------------
__global__ __launch_bounds__(256) void f32_to_f16_3(
    const float* __restrict__ s0, _Float16* __restrict__ d0, int n0,
    const float* __restrict__ s1, _Float16* __restrict__ d1, int n1,
    const float* __restrict__ s2, _Float16* __restrict__ d2, int n2)
{
  int idx = blockIdx.x * 256 + threadIdx.x;
  const float* s; _Float16* d;
  if (idx < n0)           { s = s0; d = d0; }
  else if (idx < n0 + n1) { idx -= n0; s = s1; d = d1; }
  else                    { idx -= n0 + n1; if (idx >= n2) return; s = s2; d = d2; }
  const float4 v0 = *(const float4*)(s + (size_t)idx * 8);
  const float4 v1 = *(const float4*)(s + (size_t)idx * 8 + 4);
  _Float16 h[8];
  h[0] = (_Float16)v0.x; h[1] = (_Float16)v0.y;
  h[2] = (_Float16)v0.z; h[3] = (_Float16)v0.w;
  h[4] = (_Float16)v1.x; h[5] = (_Float16)v1.y;
  h[6] = (_Float16)v1.z; h[7] = (_Float16)v1.w;
  *(uint4*)(d + (size_t)idx * 8) = *(uint4*)h;
}

// ---------------- weight-stationary fused GRU-layer GEMM, fp16 MFMA ----------------
// R5/R7-proven structure (55.8-56.1 us/dispatch over 3 independent benches):
// W frags pinned in registers (96 VGPR/lane), A streamed in 32-row chunks
// through a 3-buffer LDS ring via global_load_lds, 2-deep prefetch, ONE
// barrier + counted vmcnt(12)/chunk (12 = 4 stage + 8 stores in flight).
// Gating epilogue in-region (deferred variant raised VGPR 84->120, dropped
// occupancy 23->17% and LOST 3 us — do not defer; R11 measured).
__global__ __launch_bounds__(256, 2) void gemm_gru_f16(
    const _Float16* __restrict__ Abase, size_t a_cur_stride,
    const _Float16* __restrict__ Wbase, size_t w_cur_stride,
    const float* __restrict__ bi_g, size_t bi_stride,
    const float* __restrict__ bh_g, size_t bh_stride,
    _Float16* __restrict__ Hout)
{
  // 3 x 16 KB ring: 32 planes (pk = k0*4+q) x 32 rows x 16B each.
  __shared__ _Float16 AhS[3][8192];

  const int tid  = threadIdx.x;
  const int cu   = blockIdx.z;
  const int n0   = blockIdx.y * 64;
  const int rmb  = blockIdx.x * 512;       // this block's M range: 512 rows

  const _Float16* A = Abase + (size_t)cu * a_cur_stride;
  const _Float16* W = Wbase + (size_t)cu * w_cur_stride;
  const float* bi = bi_g + (size_t)cu * bi_stride;
  const float* bh = bh_g + (size_t)cu * bh_stride;

  const int lane = tid & 63;
  const int wv   = tid >> 6;       // wave id 0..3
  const int q    = lane >> 4;      // k-sub within frag (0..3)
  const int c    = lane & 15;      // row (A) / col (W,D) within frag

  // ---- load stationary W frags: wf[slab][k0], lane(q,c) = W[s*256+ncol][k0*32+q*8..+7]
  const int ncol = n0 + wv * 16 + c;
  f16x8 wf[3][8];
  #pragma unroll
  for (int s = 0; s < 3; s++)
    #pragma unroll
    for (int k0 = 0; k0 < 8; k0++)
      wf[s][k0] = *(const f16x8*)(W + (size_t)(s * 256 + ncol) * 256 + k0 * 32 + q * 8);
  // pin: force wf to live in VGPRs once; defeats rematerialization into the loop
  #pragma unroll
  for (int s = 0; s < 3; s++)
    #pragma unroll
    for (int k0 = 0; k0 < 8; k0++)
      asm volatile("" : "+v"(wf[s][k0]));

  // ---- biases folded into exp2 arguments (per-lane constants)
  const float c0  = -LOG2E * (bi[ncol] + bh[ncol]);
  const float c1  =  LOG2E * (bi[256 + ncol] + bh[256 + ncol]);
  const float c3  = 2.f * LOG2E * bi[512 + ncol];
  const float bhn = bh[512 + ncol];

  f32x4 acc[3][2];

  // ---- stage chunk (32 rows x 256 K) into buf: 16 x 1KB wave-instrs, 4/wave.
  auto stage = [&](int buf, int ch) {
    const int rm = rmb + ch * 32;
    #pragma unroll
    for (int i = 0; i < 4; i++) {
      const int p0 = 8 * wv + 2 * i;                 // base plane (uniform)
      const int pk = p0 + (lane >> 5);               // this lane's plane
      const _Float16* src = A + (size_t)(rm + (lane & 31)) * 256 + pk * 8;
      __builtin_amdgcn_global_load_lds(
          (const __attribute__((address_space(1))) void*)src,
          (__attribute__((address_space(3))) void*)&AhS[buf][p0 * 256],
          16, 0, 0);
    }
  };

  // ---- compute + fused gating epilogue for one chunk (8 outputs/lane)
  auto compute_chunk = [&](int buf, int ch) {
    const int rm = rmb + ch * 32;
    #pragma unroll
    for (int s = 0; s < 3; s++)
      #pragma unroll
      for (int mi = 0; mi < 2; mi++)
        acc[s][mi] = (f32x4)0.f;
    #pragma unroll
    for (int k0 = 0; k0 < 8; k0++) {
      const f16x8 a0 = *(const f16x8*)&AhS[buf][(k0 * 4 + q) * 256 + c * 8];
      const f16x8 a1 = *(const f16x8*)&AhS[buf][(k0 * 4 + q) * 256 + 128 + c * 8];
      #pragma unroll
      for (int s = 0; s < 3; s++) {
        acc[s][0] = __builtin_amdgcn_mfma_f32_16x16x32_f16(a0, wf[s][k0], acc[s][0], 0, 0, 0);
        acc[s][1] = __builtin_amdgcn_mfma_f32_16x16x32_f16(a1, wf[s][k0], acc[s][1], 0, 0, 0);
      }
    }
    #pragma unroll
    for (int mi = 0; mi < 2; mi++) {
      #pragma unroll
      for (int reg = 0; reg < 4; reg++) {
        const float ar = acc[0][mi][reg];
        const float az = acc[1][mi][reg];
        const float an = acc[2][mi][reg];
        const float e0 = __builtin_amdgcn_exp2f(fmaf(-LOG2E, ar, c0));
        const float r  = __builtin_amdgcn_rcpf(1.f + e0);
        const float e1 = __builtin_amdgcn_exp2f(fmaf(LOG2E, az, c1));
        const float tt = fmaf(r, bhn, an);
        const float a2 = fminf(fmaf(2.f * LOG2E, tt, c3), 120.f);
        const float e2 = __builtin_amdgcn_exp2f(a2);
        const float out = (e2 - 1.f) *
            __builtin_amdgcn_rcpf((1.f + e1) * (1.f + e2));
        const size_t row = (size_t)cu * Mrows + rm + mi * 16 + q * 4 + reg;
        Hout[row * 256 + ncol] = (_Float16)out;
      }
    }
  };

  // ---- prologue: 2 chunks in flight, drain chunk 0
  stage(0, 0);
  stage(1, 1);
  asm volatile("s_waitcnt vmcnt(4)" ::: "memory");
  __builtin_amdgcn_s_barrier();

  // ---- main loop: {stage(t+2) || compute(t)}, one barrier/chunk.
  // vmcnt(12) leaves exactly this iter's 12 vmem ops (4 stage + 8 stores)
  // outstanding -> drains stage(t+1), ready for compute(t+1) after barrier.
  int bc = 0;
  for (int t = 0; t < 14; ++t) {
    int bs = bc + 2; if (bs >= 3) bs -= 3;
    stage(bs, t + 2);
    compute_chunk(bc, t);
    asm volatile("s_waitcnt vmcnt(12)" ::: "memory");
    __builtin_amdgcn_s_barrier();
    bc = (bc + 1 == 3) ? 0 : bc + 1;
  }
  compute_chunk(bc, 14);                 // bc = 2 = 14%3
  asm volatile("s_waitcnt vmcnt(0)" ::: "memory");
  __builtin_amdgcn_s_barrier();
  bc = (bc + 1 == 3) ? 0 : bc + 1;       // = 0 = 15%3
  compute_chunk(bc, 15);
}

// ---------------- per-layer dot products (e, p), de-staged ----------------
__global__ __launch_bounds__(256) void ep_tile(
    const _Float16* __restrict__ Hh,
    const float* __restrict__ w_lw, const float* __restrict__ w_sel, int layer,
    float* __restrict__ e, float* __restrict__ p)
{
  __shared__ float wc[7][256];        // 7 KB
  __shared__ float ps[4][64][8];      // 8 KB partials
  const int tid = threadIdx.x;
  const size_t mg0 = (size_t)blockIdx.x * 64;

  #pragma unroll
  for (int j = 0; j < 7; j++)
    wc[j][tid] = (j < 4) ? w_lw[j * 256 + tid] : w_sel[(j - 4) * 512 + tid];
  __syncthreads();

  const int r = tid & 63, pp = tid >> 6;
  const _Float16* hrow = Hh + (mg0 + r) * 256 + pp * 64;
  float acc[7] = {0.f, 0.f, 0.f, 0.f, 0.f, 0.f, 0.f};
  #pragma unroll
  for (int i = 0; i < 8; i++) {
    union { uint4 u; _Float16 h[8]; } hv;
    hv.u = *(const uint4*)(hrow + i * 8);
    float hf[8];
    #pragma unroll
    for (int k = 0; k < 8; k++) hf[k] = (float)hv.h[k];
    #pragma unroll
    for (int j = 0; j < 7; j++) {
      const float4 w0 = *(const float4*)&wc[j][pp * 64 + i * 8];
      const float4 w1 = *(const float4*)&wc[j][pp * 64 + i * 8 + 4];
      acc[j] += hf[0] * w0.x + hf[1] * w0.y + hf[2] * w0.z + hf[3] * w0.w
              + hf[4] * w1.x + hf[5] * w1.y + hf[6] * w1.z + hf[7] * w1.w;
    }
  }
  #pragma unroll
  for (int j = 0; j < 7; j++) ps[pp][r][j] = acc[j];
  __syncthreads();

  if (tid < 64) {
    float d[7];
    #pragma unroll
    for (int j = 0; j < 7; j++)
      d[j] = ps[0][tid][j] + ps[1][tid][j] + ps[2][tid][j] + ps[3][tid][j];
    const size_t mg = mg0 + tid;
    const int cc = (int)(mg >> 15);          // / Mrows
    const int m  = (int)(mg & 32767);
    const int b = m >> 8, t = m & 255;
    const size_t base = ((size_t)cc * Tsz + t) * Bsz + b;
    #pragma unroll
    for (int j = 0; j < 4; j++) e[base * 16 + layer * 4 + j] = d[j];
    #pragma unroll
    for (int j = 0; j < 3; j++) p[base * 12 + layer * 3 + j] = d[4 + j];
  }
}

// ---------------- fused: softmax-attention scores (y<3) + xs (y==3) ----------------
__global__ __launch_bounds__(128) void attn_xs(
    const float* __restrict__ e, const float* __restrict__ p,
    const float* __restrict__ hidden, const float* __restrict__ b_lw,
    const float* __restrict__ x, const float* __restrict__ w_sel,
    const float* __restrict__ b_sel,
    float* __restrict__ score_h, float* __restrict__ xs)
{
  __shared__ float red[2][3];
  const int t = blockIdx.x;
  const int wv = threadIdx.x >> 6, ln = threadIdx.x & 63;

  if (blockIdx.y < 3) {
    const int cc = blockIdx.y;
    const int b = threadIdx.x;
    const float* eb = e + ((size_t)(cc * Tsz + t) * Bsz + b) * 16;
    const float* pb = p + ((size_t)(cc * Tsz + t) * Bsz + b) * 12;
    const float* hb = hidden + b * 16;
    const float bl0 = b_lw[0], bl1 = b_lw[1], bl2 = b_lw[2], bl3 = b_lw[3];
    float attn[4];
    #pragma unroll
    for (int i = 0; i < 4; i++) {
      attn[i] = hb[i * 4 + 0] * (eb[i * 4 + 0] + bl0)
              + hb[i * 4 + 1] * (eb[i * 4 + 1] + bl1)
              + hb[i * 4 + 2] * (eb[i * 4 + 2] + bl2)
              + hb[i * 4 + 3] * (eb[i * 4 + 3] + bl3);
    }
    const float mx = fmaxf(fmaxf(attn[0], attn[1]), fmaxf(attn[2], attn[3]));
    float ex[4], sum = 0.f;
    #pragma unroll
    for (int i = 0; i < 4; i++) { ex[i] = expf(attn[i] - mx); sum += ex[i]; }
    const float inv = 1.f / sum;
    float sc[3];
    #pragma unroll
    for (int s = 0; s < 3; s++) {
      float v = 0.f;
      #pragma unroll
      for (int i = 0; i < 4; i++) v += ex[i] * pb[i * 3 + s];
      sc[s] = v * inv;
    }
    #pragma unroll
    for (int off = 32; off; off >>= 1)
      #pragma unroll
      for (int s = 0; s < 3; s++) sc[s] += __shfl_xor(sc[s], off);
    if (ln == 0) { red[wv][0] = sc[0]; red[wv][1] = sc[1]; red[wv][2] = sc[2]; }
    __syncthreads();
    if (threadIdx.x == 0) {
      #pragma unroll
      for (int s = 0; s < 3; s++)
        score_h[((size_t)cc * Tsz + t) * 3 + s] = red[0][s] + red[1][s];
    }
  } else {
    const int k = threadIdx.x;               // handles k and k+128
    float s0 = 0.f, s1 = 0.f;
    for (int b = 0; b < Bsz; b++) {
      const float* xb = x + ((size_t)b * Tsz + t) * Isz;
      s0 += xb[k]; s1 += xb[k + 128];
    }
    float pr[3];
    #pragma unroll
    for (int qq = 0; qq < 3; qq++)
      pr[qq] = s0 * w_sel[qq * (Hsz + Isz) + Hsz + k]
             + s1 * w_sel[qq * (Hsz + Isz) + Hsz + k + 128];
    #pragma unroll
    for (int off = 32; off; off >>= 1)
      #pragma unroll
      for (int qq = 0; qq < 3; qq++) pr[qq] += __shfl_xor(pr[qq], off);
    if (ln == 0) { red[wv][0] = pr[0]; red[wv][1] = pr[1]; red[wv][2] = pr[2]; }
    __syncthreads();
    if (threadIdx.x == 0) {
      #pragma unroll
      for (int qq = 0; qq < 3; qq++)
        xs[t * 3 + qq] = red[0][qq] + red[1][qq] + (float)Bsz * b_sel[qq];
    }
  }
}

// ---------------- selector chain via parallel map-composition scan ----------------
__global__ __launch_bounds__(256) void select_kernel(
    const float* __restrict__ score_h, const float* __restrict__ xs,
    int* __restrict__ cur)
{
  __shared__ unsigned S[Tsz];
  const int t = threadIdx.x;

  unsigned m = 0x24;                     // identity map: 0->0,1->1,2->2
  if (t >= 1) {
    m = 0;
    const float* xr = xs + t * 3;
    #pragma unroll
    for (int cc = 0; cc < 3; cc++) {
      const float* sh = score_h + ((size_t)cc * Tsz + (t - 1)) * 3;
      const float v0 = sh[0] + xr[0];
      const float v1 = sh[1] + xr[1];
      const float v2 = sh[2] + xr[2];
      unsigned best = 0; float bv = v0;
      if (v1 > bv) { bv = v1; best = 1; }
      if (v2 > bv) { bv = v2; best = 2; }
      m |= best << (2 * cc);
    }
  }
  S[t] = m;
  __syncthreads();

  #pragma unroll
  for (int d = 1; d < Tsz; d <<= 1) {
    const unsigned prev = (t >= d) ? S[t - d] : 0x24u;  // identity pad
    const unsigned self = S[t];
    __syncthreads();
    unsigned comp = 0;
    #pragma unroll
    for (int xx = 0; xx < 3; xx++) {
      const unsigned y = (prev >> (2 * xx)) & 3u;
      const unsigned z = (self >> (2 * y)) & 3u;
      comp |= z << (2 * xx);
    }
    S[t] = comp;
    __syncthreads();
  }
  cur[t] = (int)(S[t] & 3u);             // composite applied to cur[0]=0
}

// ---------------- gather outputs (fp16 h -> fp32 out) ----------------
__global__ __launch_bounds__(256) void gather_out(
    const _Float16* __restrict__ Hh, const int* __restrict__ cur,
    float* __restrict__ out)
{
  const size_t idx = ((size_t)blockIdx.x * 256 + threadIdx.x) * 4;
  const size_t BTH = (size_t)Bsz * Tsz * Hsz;
  int b, t, h;
  if (idx < BTH) {
    b = (int)(idx >> 16);
    const int rem = (int)(idx & 65535);
    t = rem >> 8; h = rem & 255;
  } else {
    const size_t r2 = idx - BTH;
    b = (int)(r2 >> 8); h = (int)(r2 & 255); t = Tsz - 1;
  }
  const int cc = cur[t];
  const size_t g = (((size_t)cc * Mrows + (size_t)b * Tsz + t) * Hsz + h);
  union { ushort4 u; _Float16 hv[4]; } cv;
  cv.u = *(const ushort4*)(Hh + g);
  float4 v;
  v.x = (float)cv.hv[0]; v.y = (float)cv.hv[1];
  v.z = (float)cv.hv[2]; v.w = (float)cv.hv[3];
  *(float4*)(out + idx) = v;
}

extern "C" void kernel_launch(void* const* d_in, const int* in_sizes, int n_in,
                              void* d_out, int out_size, void* d_ws, size_t ws_size,
                              hipStream_t stream) {
  const float* x      = (const float*)d_in[0];
  const float* hidden = (const float*)d_in[1];
  const float* w_ih0  = (const float*)d_in[2];
  const float* b_ih0  = (const float*)d_in[3];
  const float* b_hh0  = (const float*)d_in[4];
  const float* w_ih   = (const float*)d_in[5];
  const float* b_ih   = (const float*)d_in[6];
  const float* b_hh   = (const float*)d_in[7];
  const float* w_lw   = (const float*)d_in[8];
  const float* b_lw   = (const float*)d_in[9];
  const float* w_sel  = (const float*)d_in[10];
  const float* b_sel  = (const float*)d_in[11];
  float* out = (float*)d_out;

  char* w = (char*)d_ws;
  const size_t HN = (size_t)3 * Mrows * 256;       // 25.2M
  const size_t XN = (size_t)Bsz * Tsz * Isz;       // 8.39M
  const size_t W0N = (size_t)3 * 768 * 256;        // 589824
  const size_t WLN = (size_t)3 * 3 * 768 * 256;    // 1769472
  _Float16* HA  = (_Float16*)w; w += HN * 2;
  _Float16* HB  = (_Float16*)w; w += HN * 2;
  _Float16* xh  = (_Float16*)w; w += XN * 2;
  _Float16* Wh0 = (_Float16*)w; w += W0N * 2;
  _Float16* WhL = (_Float16*)w; w += WLN * 2;
  float* e       = (float*)w; w += (size_t)3 * Tsz * Bsz * 16 * 4;
  float* p       = (float*)w; w += (size_t)3 * Tsz * Bsz * 12 * 4;
  float* score_h = (float*)w; w += (size_t)3 * Tsz * 3 * 4;
  float* xsb     = (float*)w; w += (size_t)Tsz * 3 * 4;
  int*   curb    = (int*)w;   w += (size_t)Tsz * 4;

  // fp32 -> fp16 conversions (one launch, 3 segments)
  f32_to_f16_3<<<5248, 256, 0, stream>>>(
      x, xh, (int)(XN / 8),
      w_ih0, Wh0, (int)(W0N / 8),
      w_ih, WhL, (int)(WLN / 8));

  // weight-stationary GEMM grid: (mseg, n-tile, cur) — R7-proven 768 blocks
  dim3 ggrid(64, 4, 3);

  // layer 0: A = xh (shared across cur)
  gemm_gru_f16<<<ggrid, 256, 0, stream>>>(
      xh, (size_t)0, Wh0, (size_t)768 * 256,
      b_ih0, (size_t)768, b_hh0, (size_t)768, HA);
  ep_tile<<<(3 * Mrows) / 64, 256, 0, stream>>>(HA, w_lw, w_sel, 0, e, p);

  const size_t wcur = (size_t)3 * 768 * 256;
  const size_t bst  = (size_t)3 * 768;
  _Float16* ping = HA; _Float16* pong = HB;
  for (int l = 1; l < 4; l++) {
    gemm_gru_f16<<<ggrid, 256, 0, stream>>>(
        ping, (size_t)Mrows * 256,
        WhL + (size_t)(l - 1) * 768 * 256, wcur,
        b_ih + (size_t)(l - 1) * 768, bst,
        b_hh + (size_t)(l - 1) * 768, bst, pong);
    ep_tile<<<(3 * Mrows) / 64, 256, 0, stream>>>(pong, w_lw, w_sel, l, e, p);
    _Float16* t1 = ping; ping = pong; pong = t1;
  }

  attn_xs<<<dim3(Tsz, 4), 128, 0, stream>>>(
      e, p, hidden, b_lw, x, w_sel, b_sel, score_h, xsb);
  select_kernel<<<1, 256, 0, stream>>>(score_h, xsb, curb);
  gather_out<<<8224, 256, 0, stream>>>(ping, curb, out);
}

// Round 14
// 365.543 us; speedup vs baseline: 1.1424x; 1.1020x over previous
//
#include <hip/hip_runtime.h>
#include <math.h>

#define Bsz 128
#define Tsz 256
#define Isz 256
#define Hsz 256
#define Lsz 4
#define Ssz 3
#define Mrows (Bsz*Tsz)   // 32768

using f16x8 = __attribute__((ext_vector_type(8))) _Float16;
using f32x4 = __attribute__((ext_vector_type(4))) float;

#define LOG2E 1.44269504f
#define GEMM_BLOCKS 768   // 64 msegs x 4 ntiles x 3 cur

// ---------------- fp32 -> fp16 convert, 3 segments in one launch ----------------
__global__ __launch_bounds__(256) void f32_to_f16_3(
    const float* __restrict__ s0, _Float16* __restrict__ d0, int n0,
    const float* __restrict__ s1, _Float16* __restrict__ d1, int n1,
    const float* __restrict__ s2, _Float16* __restrict__ d2, int n2)
{
  int idx = blockIdx.x * 256 + threadIdx.x;
  const float* s; _Float16* d;
  if (idx < n0)           { s = s0; d = d0; }
  else if (idx < n0 + n1) { idx -= n0; s = s1; d = d1; }
  else                    { idx -= n0 + n1; if (idx >= n2) return; s = s2; d = d2; }
  const float4 v0 = *(const float4*)(s + (size_t)idx * 8);
  const float4 v1 = *(const float4*)(s + (size_t)idx * 8 + 4);
  _Float16 h[8];
  h[0] = (_Float16)v0.x; h[1] = (_Float16)v0.y;
  h[2] = (_Float16)v0.z; h[3] = (_Float16)v0.w;
  h[4] = (_Float16)v1.x; h[5] = (_Float16)v1.y;
  h[6] = (_Float16)v1.z; h[7] = (_Float16)v1.w;
  *(uint4*)(d + (size_t)idx * 8) = *(uint4*)h;
}

// ---------------- weight-stationary fused GRU-layer GEMM + ep tail-backfill ----------------
// Blocks [0,768): R5/R7-proven GEMM (55.8-56.6 us over 4 benches): W frags
// pinned in registers, A streamed in 32-row chunks through a 3-buf LDS ring
// via global_load_lds, counted vmcnt(12)/chunk, in-region gating epilogue.
// Blocks [768, 2304): ep_tile body for h_{layer_ep} = this gemm's OWN A input
// (complete before launch, read-only). These blocks BACKFILL the dispatch
// tail: gemm grid = 1.5 residency rounds at 2 blocks/CU -> ~25% tail idle
// (R9 measurement); ep blocks fill it. Zero new state in gemm waves (R6's
// failure mode) and zero change to the gemm grid (R9's failure mode).
__global__ __launch_bounds__(256, 2) void gemm_gru_f16(
    const _Float16* __restrict__ Abase, size_t a_cur_stride,
    const _Float16* __restrict__ Wbase, size_t w_cur_stride,
    const float* __restrict__ bi_g, size_t bi_stride,
    const float* __restrict__ bh_g, size_t bh_stride,
    _Float16* __restrict__ Hout,
    const float* __restrict__ w_lw, const float* __restrict__ w_sel,
    float* __restrict__ e_out, float* __restrict__ p_out, int layer_ep)
{
  __shared__ __align__(16) char smem[49152];   // gemm: 3x16KB A-ring; ep: 15KB
  const int tid = threadIdx.x;
  const int bid = blockIdx.x;

  if (bid >= GEMM_BLOCKS) {
    // ================= ep backfill block (de-staged ep_tile body) =================
    float (*wc)[256]   = (float(*)[256])smem;                    // 7 KB
    float (*ps)[64][8] = (float(*)[64][8])(smem + 7 * 256 * 4);  // 8 KB
    const size_t mg0 = (size_t)(bid - GEMM_BLOCKS) * 64;

    #pragma unroll
    for (int j = 0; j < 7; j++)
      wc[j][tid] = (j < 4) ? w_lw[j * 256 + tid] : w_sel[(j - 4) * 512 + tid];
    __syncthreads();

    const int r = tid & 63, pp = tid >> 6;
    const _Float16* hrow = Abase + (mg0 + r) * 256 + pp * 64;
    float acc[7] = {0.f, 0.f, 0.f, 0.f, 0.f, 0.f, 0.f};
    #pragma unroll
    for (int i = 0; i < 8; i++) {
      union { uint4 u; _Float16 h[8]; } hv;
      hv.u = *(const uint4*)(hrow + i * 8);
      float hf[8];
      #pragma unroll
      for (int k = 0; k < 8; k++) hf[k] = (float)hv.h[k];
      #pragma unroll
      for (int j = 0; j < 7; j++) {
        const float4 w0 = *(const float4*)&wc[j][pp * 64 + i * 8];
        const float4 w1 = *(const float4*)&wc[j][pp * 64 + i * 8 + 4];
        acc[j] += hf[0] * w0.x + hf[1] * w0.y + hf[2] * w0.z + hf[3] * w0.w
                + hf[4] * w1.x + hf[5] * w1.y + hf[6] * w1.z + hf[7] * w1.w;
      }
    }
    #pragma unroll
    for (int j = 0; j < 7; j++) ps[pp][r][j] = acc[j];
    __syncthreads();

    if (tid < 64) {
      float d[7];
      #pragma unroll
      for (int j = 0; j < 7; j++)
        d[j] = ps[0][tid][j] + ps[1][tid][j] + ps[2][tid][j] + ps[3][tid][j];
      const size_t mg = mg0 + tid;
      const int cc = (int)(mg >> 15);          // / Mrows
      const int m  = (int)(mg & 32767);
      const int b = m >> 8, t = m & 255;
      const size_t base = ((size_t)cc * Tsz + t) * Bsz + b;
      #pragma unroll
      for (int j = 0; j < 4; j++) e_out[base * 16 + layer_ep * 4 + j] = d[j];
      #pragma unroll
      for (int j = 0; j < 3; j++) p_out[base * 12 + layer_ep * 3 + j] = d[4 + j];
    }
    return;
  }

  // ================= gemm block =================
  const int cu   = bid >> 8;               // 0..2
  const int n0   = ((bid >> 6) & 3) * 64;  // n-tile
  const int rmb  = (bid & 63) * 512;       // mseg (x-fastest, same as R13)

  _Float16 (*AhS)[8192] = (_Float16(*)[8192])smem;

  const _Float16* A = Abase + (size_t)cu * a_cur_stride;
  const _Float16* W = Wbase + (size_t)cu * w_cur_stride;
  const float* bi = bi_g + (size_t)cu * bi_stride;
  const float* bh = bh_g + (size_t)cu * bh_stride;

  const int lane = tid & 63;
  const int wv   = tid >> 6;       // wave id 0..3
  const int q    = lane >> 4;      // k-sub within frag (0..3)
  const int c    = lane & 15;      // row (A) / col (W,D) within frag

  // ---- load stationary W frags: wf[slab][k0], lane(q,c) = W[s*256+ncol][k0*32+q*8..+7]
  const int ncol = n0 + wv * 16 + c;
  f16x8 wf[3][8];
  #pragma unroll
  for (int s = 0; s < 3; s++)
    #pragma unroll
    for (int k0 = 0; k0 < 8; k0++)
      wf[s][k0] = *(const f16x8*)(W + (size_t)(s * 256 + ncol) * 256 + k0 * 32 + q * 8);
  // pin: force wf to live in VGPRs once; defeats rematerialization into the loop
  #pragma unroll
  for (int s = 0; s < 3; s++)
    #pragma unroll
    for (int k0 = 0; k0 < 8; k0++)
      asm volatile("" : "+v"(wf[s][k0]));

  // ---- biases folded into exp2 arguments (per-lane constants)
  const float c0  = -LOG2E * (bi[ncol] + bh[ncol]);
  const float c1  =  LOG2E * (bi[256 + ncol] + bh[256 + ncol]);
  const float c3  = 2.f * LOG2E * bi[512 + ncol];
  const float bhn = bh[512 + ncol];

  f32x4 acc[3][2];

  // ---- stage chunk (32 rows x 256 K) into buf: 16 x 1KB wave-instrs, 4/wave.
  auto stage = [&](int buf, int ch) {
    const int rm = rmb + ch * 32;
    #pragma unroll
    for (int i = 0; i < 4; i++) {
      const int p0 = 8 * wv + 2 * i;                 // base plane (uniform)
      const int pk = p0 + (lane >> 5);               // this lane's plane
      const _Float16* src = A + (size_t)(rm + (lane & 31)) * 256 + pk * 8;
      __builtin_amdgcn_global_load_lds(
          (const __attribute__((address_space(1))) void*)src,
          (__attribute__((address_space(3))) void*)&AhS[buf][p0 * 256],
          16, 0, 0);
    }
  };

  // ---- compute + fused gating epilogue for one chunk (8 outputs/lane)
  auto compute_chunk = [&](int buf, int ch) {
    const int rm = rmb + ch * 32;
    #pragma unroll
    for (int s = 0; s < 3; s++)
      #pragma unroll
      for (int mi = 0; mi < 2; mi++)
        acc[s][mi] = (f32x4)0.f;
    #pragma unroll
    for (int k0 = 0; k0 < 8; k0++) {
      const f16x8 a0 = *(const f16x8*)&AhS[buf][(k0 * 4 + q) * 256 + c * 8];
      const f16x8 a1 = *(const f16x8*)&AhS[buf][(k0 * 4 + q) * 256 + 128 + c * 8];
      #pragma unroll
      for (int s = 0; s < 3; s++) {
        acc[s][0] = __builtin_amdgcn_mfma_f32_16x16x32_f16(a0, wf[s][k0], acc[s][0], 0, 0, 0);
        acc[s][1] = __builtin_amdgcn_mfma_f32_16x16x32_f16(a1, wf[s][k0], acc[s][1], 0, 0, 0);
      }
    }
    #pragma unroll
    for (int mi = 0; mi < 2; mi++) {
      #pragma unroll
      for (int reg = 0; reg < 4; reg++) {
        const float ar = acc[0][mi][reg];
        const float az = acc[1][mi][reg];
        const float an = acc[2][mi][reg];
        const float e0 = __builtin_amdgcn_exp2f(fmaf(-LOG2E, ar, c0));
        const float r  = __builtin_amdgcn_rcpf(1.f + e0);
        const float e1 = __builtin_amdgcn_exp2f(fmaf(LOG2E, az, c1));
        const float tt = fmaf(r, bhn, an);
        const float a2 = fminf(fmaf(2.f * LOG2E, tt, c3), 120.f);
        const float e2 = __builtin_amdgcn_exp2f(a2);
        const float out = (e2 - 1.f) *
            __builtin_amdgcn_rcpf((1.f + e1) * (1.f + e2));
        const size_t row = (size_t)cu * Mrows + rm + mi * 16 + q * 4 + reg;
        Hout[row * 256 + ncol] = (_Float16)out;
      }
    }
  };

  // ---- prologue: 2 chunks in flight, drain chunk 0
  stage(0, 0);
  stage(1, 1);
  asm volatile("s_waitcnt vmcnt(4)" ::: "memory");
  __builtin_amdgcn_s_barrier();

  // ---- main loop: {stage(t+2) || compute(t)}, one barrier/chunk.
  // vmcnt(12) leaves exactly this iter's 12 vmem ops (4 stage + 8 stores)
  // outstanding -> drains stage(t+1), ready for compute(t+1) after barrier.
  int bc = 0;
  for (int t = 0; t < 14; ++t) {
    int bs = bc + 2; if (bs >= 3) bs -= 3;
    stage(bs, t + 2);
    compute_chunk(bc, t);
    asm volatile("s_waitcnt vmcnt(12)" ::: "memory");
    __builtin_amdgcn_s_barrier();
    bc = (bc + 1 == 3) ? 0 : bc + 1;
  }
  compute_chunk(bc, 14);                 // bc = 2 = 14%3
  asm volatile("s_waitcnt vmcnt(0)" ::: "memory");
  __builtin_amdgcn_s_barrier();
  bc = (bc + 1 == 3) ? 0 : bc + 1;       // = 0 = 15%3
  compute_chunk(bc, 15);
}

// ---------------- per-layer dot products (e, p), de-staged — layer 3 only ----------------
__global__ __launch_bounds__(256) void ep_tile(
    const _Float16* __restrict__ Hh,
    const float* __restrict__ w_lw, const float* __restrict__ w_sel, int layer,
    float* __restrict__ e, float* __restrict__ p)
{
  __shared__ float wc[7][256];        // 7 KB
  __shared__ float ps[4][64][8];      // 8 KB partials
  const int tid = threadIdx.x;
  const size_t mg0 = (size_t)blockIdx.x * 64;

  #pragma unroll
  for (int j = 0; j < 7; j++)
    wc[j][tid] = (j < 4) ? w_lw[j * 256 + tid] : w_sel[(j - 4) * 512 + tid];
  __syncthreads();

  const int r = tid & 63, pp = tid >> 6;
  const _Float16* hrow = Hh + (mg0 + r) * 256 + pp * 64;
  float acc[7] = {0.f, 0.f, 0.f, 0.f, 0.f, 0.f, 0.f};
  #pragma unroll
  for (int i = 0; i < 8; i++) {
    union { uint4 u; _Float16 h[8]; } hv;
    hv.u = *(const uint4*)(hrow + i * 8);
    float hf[8];
    #pragma unroll
    for (int k = 0; k < 8; k++) hf[k] = (float)hv.h[k];
    #pragma unroll
    for (int j = 0; j < 7; j++) {
      const float4 w0 = *(const float4*)&wc[j][pp * 64 + i * 8];
      const float4 w1 = *(const float4*)&wc[j][pp * 64 + i * 8 + 4];
      acc[j] += hf[0] * w0.x + hf[1] * w0.y + hf[2] * w0.z + hf[3] * w0.w
              + hf[4] * w1.x + hf[5] * w1.y + hf[6] * w1.z + hf[7] * w1.w;
    }
  }
  #pragma unroll
  for (int j = 0; j < 7; j++) ps[pp][r][j] = acc[j];
  __syncthreads();

  if (tid < 64) {
    float d[7];
    #pragma unroll
    for (int j = 0; j < 7; j++)
      d[j] = ps[0][tid][j] + ps[1][tid][j] + ps[2][tid][j] + ps[3][tid][j];
    const size_t mg = mg0 + tid;
    const int cc = (int)(mg >> 15);          // / Mrows
    const int m  = (int)(mg & 32767);
    const int b = m >> 8, t = m & 255;
    const size_t base = ((size_t)cc * Tsz + t) * Bsz + b;
    #pragma unroll
    for (int j = 0; j < 4; j++) e[base * 16 + layer * 4 + j] = d[j];
    #pragma unroll
    for (int j = 0; j < 3; j++) p[base * 12 + layer * 3 + j] = d[4 + j];
  }
}

// ---------------- fused: softmax-attention scores (y<3) + xs (y==3) ----------------
__global__ __launch_bounds__(128) void attn_xs(
    const float* __restrict__ e, const float* __restrict__ p,
    const float* __restrict__ hidden, const float* __restrict__ b_lw,
    const float* __restrict__ x, const float* __restrict__ w_sel,
    const float* __restrict__ b_sel,
    float* __restrict__ score_h, float* __restrict__ xs)
{
  __shared__ float red[2][3];
  const int t = blockIdx.x;
  const int wv = threadIdx.x >> 6, ln = threadIdx.x & 63;

  if (blockIdx.y < 3) {
    const int cc = blockIdx.y;
    const int b = threadIdx.x;
    const float* eb = e + ((size_t)(cc * Tsz + t) * Bsz + b) * 16;
    const float* pb = p + ((size_t)(cc * Tsz + t) * Bsz + b) * 12;
    const float* hb = hidden + b * 16;
    const float bl0 = b_lw[0], bl1 = b_lw[1], bl2 = b_lw[2], bl3 = b_lw[3];
    float attn[4];
    #pragma unroll
    for (int i = 0; i < 4; i++) {
      attn[i] = hb[i * 4 + 0] * (eb[i * 4 + 0] + bl0)
              + hb[i * 4 + 1] * (eb[i * 4 + 1] + bl1)
              + hb[i * 4 + 2] * (eb[i * 4 + 2] + bl2)
              + hb[i * 4 + 3] * (eb[i * 4 + 3] + bl3);
    }
    const float mx = fmaxf(fmaxf(attn[0], attn[1]), fmaxf(attn[2], attn[3]));
    float ex[4], sum = 0.f;
    #pragma unroll
    for (int i = 0; i < 4; i++) { ex[i] = expf(attn[i] - mx); sum += ex[i]; }
    const float inv = 1.f / sum;
    float sc[3];
    #pragma unroll
    for (int s = 0; s < 3; s++) {
      float v = 0.f;
      #pragma unroll
      for (int i = 0; i < 4; i++) v += ex[i] * pb[i * 3 + s];
      sc[s] = v * inv;
    }
    #pragma unroll
    for (int off = 32; off; off >>= 1)
      #pragma unroll
      for (int s = 0; s < 3; s++) sc[s] += __shfl_xor(sc[s], off);
    if (ln == 0) { red[wv][0] = sc[0]; red[wv][1] = sc[1]; red[wv][2] = sc[2]; }
    __syncthreads();
    if (threadIdx.x == 0) {
      #pragma unroll
      for (int s = 0; s < 3; s++)
        score_h[((size_t)cc * Tsz + t) * 3 + s] = red[0][s] + red[1][s];
    }
  } else {
    const int k = threadIdx.x;               // handles k and k+128
    float s0 = 0.f, s1 = 0.f;
    for (int b = 0; b < Bsz; b++) {
      const float* xb = x + ((size_t)b * Tsz + t) * Isz;
      s0 += xb[k]; s1 += xb[k + 128];
    }
    float pr[3];
    #pragma unroll
    for (int qq = 0; qq < 3; qq++)
      pr[qq] = s0 * w_sel[qq * (Hsz + Isz) + Hsz + k]
             + s1 * w_sel[qq * (Hsz + Isz) + Hsz + k + 128];
    #pragma unroll
    for (int off = 32; off; off >>= 1)
      #pragma unroll
      for (int qq = 0; qq < 3; qq++) pr[qq] += __shfl_xor(pr[qq], off);
    if (ln == 0) { red[wv][0] = pr[0]; red[wv][1] = pr[1]; red[wv][2] = pr[2]; }
    __syncthreads();
    if (threadIdx.x == 0) {
      #pragma unroll
      for (int qq = 0; qq < 3; qq++)
        xs[t * 3 + qq] = red[0][qq] + red[1][qq] + (float)Bsz * b_sel[qq];
    }
  }
}

// ---------------- selector chain via parallel map-composition scan ----------------
__global__ __launch_bounds__(256) void select_kernel(
    const float* __restrict__ score_h, const float* __restrict__ xs,
    int* __restrict__ cur)
{
  __shared__ unsigned S[Tsz];
  const int t = threadIdx.x;

  unsigned m = 0x24;                     // identity map: 0->0,1->1,2->2
  if (t >= 1) {
    m = 0;
    const float* xr = xs + t * 3;
    #pragma unroll
    for (int cc = 0; cc < 3; cc++) {
      const float* sh = score_h + ((size_t)cc * Tsz + (t - 1)) * 3;
      const float v0 = sh[0] + xr[0];
      const float v1 = sh[1] + xr[1];
      const float v2 = sh[2] + xr[2];
      unsigned best = 0; float bv = v0;
      if (v1 > bv) { bv = v1; best = 1; }
      if (v2 > bv) { bv = v2; best = 2; }
      m |= best << (2 * cc);
    }
  }
  S[t] = m;
  __syncthreads();

  #pragma unroll
  for (int d = 1; d < Tsz; d <<= 1) {
    const unsigned prev = (t >= d) ? S[t - d] : 0x24u;  // identity pad
    const unsigned self = S[t];
    __syncthreads();
    unsigned comp = 0;
    #pragma unroll
    for (int xx = 0; xx < 3; xx++) {
      const unsigned y = (prev >> (2 * xx)) & 3u;
      const unsigned z = (self >> (2 * y)) & 3u;
      comp |= z << (2 * xx);
    }
    S[t] = comp;
    __syncthreads();
  }
  cur[t] = (int)(S[t] & 3u);             // composite applied to cur[0]=0
}

// ---------------- gather outputs (fp16 h -> fp32 out) ----------------
__global__ __launch_bounds__(256) void gather_out(
    const _Float16* __restrict__ Hh, const int* __restrict__ cur,
    float* __restrict__ out)
{
  const size_t idx = ((size_t)blockIdx.x * 256 + threadIdx.x) * 4;
  const size_t BTH = (size_t)Bsz * Tsz * Hsz;
  int b, t, h;
  if (idx < BTH) {
    b = (int)(idx >> 16);
    const int rem = (int)(idx & 65535);
    t = rem >> 8; h = rem & 255;
  } else {
    const size_t r2 = idx - BTH;
    b = (int)(r2 >> 8); h = (int)(r2 & 255); t = Tsz - 1;
  }
  const int cc = cur[t];
  const size_t g = (((size_t)cc * Mrows + (size_t)b * Tsz + t) * Hsz + h);
  union { ushort4 u; _Float16 hv[4]; } cv;
  cv.u = *(const ushort4*)(Hh + g);
  float4 v;
  v.x = (float)cv.hv[0]; v.y = (float)cv.hv[1];
  v.z = (float)cv.hv[2]; v.w = (float)cv.hv[3];
  *(float4*)(out + idx) = v;
}

extern "C" void kernel_launch(void* const* d_in, const int* in_sizes, int n_in,
                              void* d_out, int out_size, void* d_ws, size_t ws_size,
                              hipStream_t stream) {
  const float* x      = (const float*)d_in[0];
  const float* hidden = (const float*)d_in[1];
  const float* w_ih0  = (const float*)d_in[2];
  const float* b_ih0  = (const float*)d_in[3];
  const float* b_hh0  = (const float*)d_in[4];
  const float* w_ih   = (const float*)d_in[5];
  const float* b_ih   = (const float*)d_in[6];
  const float* b_hh   = (const float*)d_in[7];
  const float* w_lw   = (const float*)d_in[8];
  const float* b_lw   = (const float*)d_in[9];
  const float* w_sel  = (const float*)d_in[10];
  const float* b_sel  = (const float*)d_in[11];
  float* out = (float*)d_out;

  char* w = (char*)d_ws;
  const size_t HN = (size_t)3 * Mrows * 256;       // 25.2M
  const size_t XN = (size_t)Bsz * Tsz * Isz;       // 8.39M
  const size_t W0N = (size_t)3 * 768 * 256;        // 589824
  const size_t WLN = (size_t)3 * 3 * 768 * 256;    // 1769472
  _Float16* HA  = (_Float16*)w; w += HN * 2;
  _Float16* HB  = (_Float16*)w; w += HN * 2;
  _Float16* xh  = (_Float16*)w; w += XN * 2;
  _Float16* Wh0 = (_Float16*)w; w += W0N * 2;
  _Float16* WhL = (_Float16*)w; w += WLN * 2;
  float* e       = (float*)w; w += (size_t)3 * Tsz * Bsz * 16 * 4;
  float* p       = (float*)w; w += (size_t)3 * Tsz * Bsz * 12 * 4;
  float* score_h = (float*)w; w += (size_t)3 * Tsz * 3 * 4;
  float* xsb     = (float*)w; w += (size_t)Tsz * 3 * 4;
  int*   curb    = (int*)w;   w += (size_t)Tsz * 4;

  // fp32 -> fp16 conversions (one launch, 3 segments)
  f32_to_f16_3<<<5248, 256, 0, stream>>>(
      x, xh, (int)(XN / 8),
      w_ih0, Wh0, (int)(W0N / 8),
      w_ih, WhL, (int)(WLN / 8));

  // layer 0: A = xh (shared across cur), gemm blocks only
  gemm_gru_f16<<<GEMM_BLOCKS, 256, 0, stream>>>(
      xh, (size_t)0, Wh0, (size_t)768 * 256,
      b_ih0, (size_t)768, b_hh0, (size_t)768, HA,
      nullptr, nullptr, nullptr, nullptr, -1);

  const size_t wcur = (size_t)3 * 768 * 256;
  const size_t bst  = (size_t)3 * 768;
  _Float16* ping = HA; _Float16* pong = HB;
  for (int l = 1; l < 4; l++) {
    // gemm(l) + tail-backfilled ep(l-1) over A = h_{l-1} (= ping)
    gemm_gru_f16<<<GEMM_BLOCKS + 1536, 256, 0, stream>>>(
        ping, (size_t)Mrows * 256,
        WhL + (size_t)(l - 1) * 768 * 256, wcur,
        b_ih + (size_t)(l - 1) * 768, bst,
        b_hh + (size_t)(l - 1) * 768, bst, pong,
        w_lw, w_sel, e, p, l - 1);
    _Float16* t1 = ping; ping = pong; pong = t1;
  }
  // ep for layer 3 (no following gemm to backfill)
  ep_tile<<<(3 * Mrows) / 64, 256, 0, stream>>>(ping, w_lw, w_sel, 3, e, p);

  attn_xs<<<dim3(Tsz, 4), 128, 0, stream>>>(
      e, p, hidden, b_lw, x, w_sel, b_sel, score_h, xsb);
  select_kernel<<<1, 256, 0, stream>>>(score_h, xsb, curb);
  gather_out<<<8224, 256, 0, stream>>>(ping, curb, out);
}

// Round 16
// 359.417 us; speedup vs baseline: 1.1619x; 1.0170x over previous
//
#include <hip/hip_runtime.h>
#include <math.h>

#define Bsz 128
#define Tsz 256
#define Isz 256
#define Hsz 256
#define Lsz 4
#define Ssz 3
#define Mrows (Bsz*Tsz)   // 32768

using f16x8 = __attribute__((ext_vector_type(8))) _Float16;
using f32x4 = __attribute__((ext_vector_type(4))) float;

#define LOG2E 1.44269504f
#define GEMM_BLOCKS 768   // 64 msegs x 4 ntiles x 3 cur

// ---------------- fp32 -> fp16 convert, 3 segments in one launch ----------------
__global__ __launch_bounds__(256) void f32_to_f16_3(
    const float* __restrict__ s0, _Float16* __restrict__ d0, int n0,
    const float* __restrict__ s1, _Float16* __restrict__ d1, int n1,
    const float* __restrict__ s2, _Float16* __restrict__ d2, int n2)
{
  int idx = blockIdx.x * 256 + threadIdx.x;
  const float* s; _Float16* d;
  if (idx < n0)           { s = s0; d = d0; }
  else if (idx < n0 + n1) { idx -= n0; s = s1; d = d1; }
  else                    { idx -= n0 + n1; if (idx >= n2) return; s = s2; d = d2; }
  const float4 v0 = *(const float4*)(s + (size_t)idx * 8);
  const float4 v1 = *(const float4*)(s + (size_t)idx * 8 + 4);
  _Float16 h[8];
  h[0] = (_Float16)v0.x; h[1] = (_Float16)v0.y;
  h[2] = (_Float16)v0.z; h[3] = (_Float16)v0.w;
  h[4] = (_Float16)v1.x; h[5] = (_Float16)v1.y;
  h[6] = (_Float16)v1.z; h[7] = (_Float16)v1.w;
  *(uint4*)(d + (size_t)idx * 8) = *(uint4*)h;
}

// ---------------- weight-stationary fused GRU-layer GEMM + ep tail-backfill ----------------
// R14-proven (365.5 us total, passed): blocks [0,768) = R5/R7 GEMM; blocks
// [768,2304) = ep_tile body for this gemm's OWN A input (backfills the
// dispatch tail). Byte-identical to R14.
__global__ __launch_bounds__(256, 2) void gemm_gru_f16(
    const _Float16* __restrict__ Abase, size_t a_cur_stride,
    const _Float16* __restrict__ Wbase, size_t w_cur_stride,
    const float* __restrict__ bi_g, size_t bi_stride,
    const float* __restrict__ bh_g, size_t bh_stride,
    _Float16* __restrict__ Hout,
    const float* __restrict__ w_lw, const float* __restrict__ w_sel,
    float* __restrict__ e_out, float* __restrict__ p_out, int layer_ep)
{
  __shared__ __align__(16) char smem[49152];   // gemm: 3x16KB A-ring; ep: 15KB
  const int tid = threadIdx.x;
  const int bid = blockIdx.x;

  if (bid >= GEMM_BLOCKS) {
    // ================= ep backfill block (de-staged ep_tile body) =================
    float (*wc)[256]   = (float(*)[256])smem;                    // 7 KB
    float (*ps)[64][8] = (float(*)[64][8])(smem + 7 * 256 * 4);  // 8 KB
    const size_t mg0 = (size_t)(bid - GEMM_BLOCKS) * 64;

    #pragma unroll
    for (int j = 0; j < 7; j++)
      wc[j][tid] = (j < 4) ? w_lw[j * 256 + tid] : w_sel[(j - 4) * 512 + tid];
    __syncthreads();

    const int r = tid & 63, pp = tid >> 6;
    const _Float16* hrow = Abase + (mg0 + r) * 256 + pp * 64;
    float acc[7] = {0.f, 0.f, 0.f, 0.f, 0.f, 0.f, 0.f};
    #pragma unroll
    for (int i = 0; i < 8; i++) {
      union { uint4 u; _Float16 h[8]; } hv;
      hv.u = *(const uint4*)(hrow + i * 8);
      float hf[8];
      #pragma unroll
      for (int k = 0; k < 8; k++) hf[k] = (float)hv.h[k];
      #pragma unroll
      for (int j = 0; j < 7; j++) {
        const float4 w0 = *(const float4*)&wc[j][pp * 64 + i * 8];
        const float4 w1 = *(const float4*)&wc[j][pp * 64 + i * 8 + 4];
        acc[j] += hf[0] * w0.x + hf[1] * w0.y + hf[2] * w0.z + hf[3] * w0.w
                + hf[4] * w1.x + hf[5] * w1.y + hf[6] * w1.z + hf[7] * w1.w;
      }
    }
    #pragma unroll
    for (int j = 0; j < 7; j++) ps[pp][r][j] = acc[j];
    __syncthreads();

    if (tid < 64) {
      float d[7];
      #pragma unroll
      for (int j = 0; j < 7; j++)
        d[j] = ps[0][tid][j] + ps[1][tid][j] + ps[2][tid][j] + ps[3][tid][j];
      const size_t mg = mg0 + tid;
      const int cc = (int)(mg >> 15);          // / Mrows
      const int m  = (int)(mg & 32767);
      const int b = m >> 8, t = m & 255;
      const size_t base = ((size_t)cc * Tsz + t) * Bsz + b;
      #pragma unroll
      for (int j = 0; j < 4; j++) e_out[base * 16 + layer_ep * 4 + j] = d[j];
      #pragma unroll
      for (int j = 0; j < 3; j++) p_out[base * 12 + layer_ep * 3 + j] = d[4 + j];
    }
    return;
  }

  // ================= gemm block =================
  const int cu   = bid >> 8;               // 0..2
  const int n0   = ((bid >> 6) & 3) * 64;  // n-tile
  const int rmb  = (bid & 63) * 512;       // mseg (x-fastest)

  _Float16 (*AhS)[8192] = (_Float16(*)[8192])smem;

  const _Float16* A = Abase + (size_t)cu * a_cur_stride;
  const _Float16* W = Wbase + (size_t)cu * w_cur_stride;
  const float* bi = bi_g + (size_t)cu * bi_stride;
  const float* bh = bh_g + (size_t)cu * bh_stride;

  const int lane = tid & 63;
  const int wv   = tid >> 6;       // wave id 0..3
  const int q    = lane >> 4;      // k-sub within frag (0..3)
  const int c    = lane & 15;      // row (A) / col (W,D) within frag

  // ---- load stationary W frags
  const int ncol = n0 + wv * 16 + c;
  f16x8 wf[3][8];
  #pragma unroll
  for (int s = 0; s < 3; s++)
    #pragma unroll
    for (int k0 = 0; k0 < 8; k0++)
      wf[s][k0] = *(const f16x8*)(W + (size_t)(s * 256 + ncol) * 256 + k0 * 32 + q * 8);
  #pragma unroll
  for (int s = 0; s < 3; s++)
    #pragma unroll
    for (int k0 = 0; k0 < 8; k0++)
      asm volatile("" : "+v"(wf[s][k0]));

  // ---- biases folded into exp2 arguments
  const float c0  = -LOG2E * (bi[ncol] + bh[ncol]);
  const float c1  =  LOG2E * (bi[256 + ncol] + bh[256 + ncol]);
  const float c3  = 2.f * LOG2E * bi[512 + ncol];
  const float bhn = bh[512 + ncol];

  f32x4 acc[3][2];

  auto stage = [&](int buf, int ch) {
    const int rm = rmb + ch * 32;
    #pragma unroll
    for (int i = 0; i < 4; i++) {
      const int p0 = 8 * wv + 2 * i;                 // base plane (uniform)
      const int pk = p0 + (lane >> 5);               // this lane's plane
      const _Float16* src = A + (size_t)(rm + (lane & 31)) * 256 + pk * 8;
      __builtin_amdgcn_global_load_lds(
          (const __attribute__((address_space(1))) void*)src,
          (__attribute__((address_space(3))) void*)&AhS[buf][p0 * 256],
          16, 0, 0);
    }
  };

  auto compute_chunk = [&](int buf, int ch) {
    const int rm = rmb + ch * 32;
    #pragma unroll
    for (int s = 0; s < 3; s++)
      #pragma unroll
      for (int mi = 0; mi < 2; mi++)
        acc[s][mi] = (f32x4)0.f;
    #pragma unroll
    for (int k0 = 0; k0 < 8; k0++) {
      const f16x8 a0 = *(const f16x8*)&AhS[buf][(k0 * 4 + q) * 256 + c * 8];
      const f16x8 a1 = *(const f16x8*)&AhS[buf][(k0 * 4 + q) * 256 + 128 + c * 8];
      #pragma unroll
      for (int s = 0; s < 3; s++) {
        acc[s][0] = __builtin_amdgcn_mfma_f32_16x16x32_f16(a0, wf[s][k0], acc[s][0], 0, 0, 0);
        acc[s][1] = __builtin_amdgcn_mfma_f32_16x16x32_f16(a1, wf[s][k0], acc[s][1], 0, 0, 0);
      }
    }
    #pragma unroll
    for (int mi = 0; mi < 2; mi++) {
      #pragma unroll
      for (int reg = 0; reg < 4; reg++) {
        const float ar = acc[0][mi][reg];
        const float az = acc[1][mi][reg];
        const float an = acc[2][mi][reg];
        const float e0 = __builtin_amdgcn_exp2f(fmaf(-LOG2E, ar, c0));
        const float r  = __builtin_amdgcn_rcpf(1.f + e0);
        const float e1 = __builtin_amdgcn_exp2f(fmaf(LOG2E, az, c1));
        const float tt = fmaf(r, bhn, an);
        const float a2 = fminf(fmaf(2.f * LOG2E, tt, c3), 120.f);
        const float e2 = __builtin_amdgcn_exp2f(a2);
        const float out = (e2 - 1.f) *
            __builtin_amdgcn_rcpf((1.f + e1) * (1.f + e2));
        const size_t row = (size_t)cu * Mrows + rm + mi * 16 + q * 4 + reg;
        Hout[row * 256 + ncol] = (_Float16)out;
      }
    }
  };

  // ---- prologue: 2 chunks in flight, drain chunk 0
  stage(0, 0);
  stage(1, 1);
  asm volatile("s_waitcnt vmcnt(4)" ::: "memory");
  __builtin_amdgcn_s_barrier();

  // ---- main loop: {stage(t+2) || compute(t)}, one barrier/chunk.
  int bc = 0;
  for (int t = 0; t < 14; ++t) {
    int bs = bc + 2; if (bs >= 3) bs -= 3;
    stage(bs, t + 2);
    compute_chunk(bc, t);
    asm volatile("s_waitcnt vmcnt(12)" ::: "memory");
    __builtin_amdgcn_s_barrier();
    bc = (bc + 1 == 3) ? 0 : bc + 1;
  }
  compute_chunk(bc, 14);                 // bc = 2 = 14%3
  asm volatile("s_waitcnt vmcnt(0)" ::: "memory");
  __builtin_amdgcn_s_barrier();
  bc = (bc + 1 == 3) ? 0 : bc + 1;       // = 0 = 15%3
  compute_chunk(bc, 15);
}

// ---------------- fused: layer-3 ep (in-block, ep_tile-exact order) + attn; xs ----------------
// grid (Tsz, 4), 256 threads. Blocks y<3 = (t, cc): thread pair (b, b+128)
// computes the 4 K-quarters of the layer-3 e/p dots with EXACTLY ep_tile's
// summation order (((q0+q1)+q2)+q3, same inner chains), then waves 0-1 run
// the R14-exact attn softmax (d-term added LAST in sc, as R14's pb[9+s]).
// Block y==3: R14-exact xs (tid<128 active). All deps intra-block.
__global__ __launch_bounds__(256) void attn_ep_xs(
    const _Float16* __restrict__ Hh,
    const float* __restrict__ e, const float* __restrict__ p,
    const float* __restrict__ hidden, const float* __restrict__ b_lw,
    const float* __restrict__ x, const float* __restrict__ w_sel,
    const float* __restrict__ b_sel, const float* __restrict__ w_lw,
    float* __restrict__ score_h, float* __restrict__ xs)
{
  __shared__ float wc[7][256];       // 7 KB
  __shared__ float ps[128][2][7];    // 3.5 KB (hi-thread quarters)
  __shared__ float red[2][3];
  const int tid = threadIdx.x;
  const int t = blockIdx.x;
  const int lane = tid & 63, wid = tid >> 6;

  if (blockIdx.y < 3) {
    const int cc = blockIdx.y;
    #pragma unroll
    for (int j = 0; j < 7; j++)
      wc[j][tid] = (j < 4) ? w_lw[j * 256 + tid] : w_sel[(j - 4) * 512 + tid];
    __syncthreads();

    const int b  = tid & 127;
    const int hi = tid >> 7;           // 0: quarters 0,1; 1: quarters 2,3
    const _Float16* hrow =
        Hh + ((size_t)cc * Mrows + (size_t)b * Tsz + t) * 256;

    float qa[7] = {0.f,0.f,0.f,0.f,0.f,0.f,0.f};
    float qb[7] = {0.f,0.f,0.f,0.f,0.f,0.f,0.f};
    auto quarter = [&](float (&qacc)[7], int pp) {   // pp = K-quarter index
      #pragma unroll
      for (int i = 0; i < 8; i++) {
        union { uint4 u; _Float16 hh[8]; } hv;
        hv.u = *(const uint4*)(hrow + pp * 64 + i * 8);
        float hf[8];
        #pragma unroll
        for (int k = 0; k < 8; k++) hf[k] = (float)hv.hh[k];
        #pragma unroll
        for (int j = 0; j < 7; j++) {
          const float4 w0 = *(const float4*)&wc[j][pp * 64 + i * 8];
          const float4 w1 = *(const float4*)&wc[j][pp * 64 + i * 8 + 4];
          qacc[j] += hf[0]*w0.x + hf[1]*w0.y + hf[2]*w0.z + hf[3]*w0.w
                   + hf[4]*w1.x + hf[5]*w1.y + hf[6]*w1.z + hf[7]*w1.w;
        }
      }
    };
    quarter(qa, hi * 2);
    quarter(qb, hi * 2 + 1);

    if (hi) {
      #pragma unroll
      for (int j = 0; j < 7; j++) { ps[b][0][j] = qa[j]; ps[b][1][j] = qb[j]; }
    }
    __syncthreads();
    if (!hi) {
      float d[7];
      #pragma unroll
      for (int j = 0; j < 7; j++)
        d[j] = ((qa[j] + qb[j]) + ps[b][0][j]) + ps[b][1][j];  // ep_tile order

      const size_t base = ((size_t)cc * Tsz + t) * Bsz + b;
      const float* eb = e + base * 16;
      const float* pb = p + base * 12;
      const float* hb = hidden + b * 16;
      const float bl0 = b_lw[0], bl1 = b_lw[1], bl2 = b_lw[2], bl3 = b_lw[3];
      float attn[4];
      #pragma unroll
      for (int i = 0; i < 3; i++) {
        attn[i] = hb[i*4+0]*(eb[i*4+0]+bl0) + hb[i*4+1]*(eb[i*4+1]+bl1)
                + hb[i*4+2]*(eb[i*4+2]+bl2) + hb[i*4+3]*(eb[i*4+3]+bl3);
      }
      attn[3] = hb[12]*(d[0]+bl0) + hb[13]*(d[1]+bl1)
              + hb[14]*(d[2]+bl2) + hb[15]*(d[3]+bl3);
      const float mx = fmaxf(fmaxf(attn[0],attn[1]), fmaxf(attn[2],attn[3]));
      float ex[4], sum = 0.f;
      #pragma unroll
      for (int i = 0; i < 4; i++) { ex[i] = expf(attn[i]-mx); sum += ex[i]; }
      const float inv = 1.f / sum;
      float sc[3];
      #pragma unroll
      for (int s = 0; s < 3; s++) {
        float v = 0.f;
        #pragma unroll
        for (int i = 0; i < 3; i++) v += ex[i] * pb[i*3+s];
        v += ex[3] * d[4+s];               // layer-3 term LAST (R14 order)
        sc[s] = v * inv;
      }
      #pragma unroll
      for (int off = 32; off; off >>= 1)
        #pragma unroll
        for (int s = 0; s < 3; s++) sc[s] += __shfl_xor(sc[s], off);
      if (lane == 0) { red[wid][0]=sc[0]; red[wid][1]=sc[1]; red[wid][2]=sc[2]; }
    }
    __syncthreads();
    if (tid == 0) {
      #pragma unroll
      for (int s = 0; s < 3; s++)
        score_h[((size_t)cc * Tsz + t) * 3 + s] = red[0][s] + red[1][s];
    }
  } else {
    // ---- xs: R14-exact (128 active threads, waves 0-1)
    if (tid < 128) {
      const int k = tid;
      float s0 = 0.f, s1 = 0.f;
      for (int b2 = 0; b2 < Bsz; b2++) {
        const float* xb = x + ((size_t)b2 * Tsz + t) * Isz;
        s0 += xb[k]; s1 += xb[k + 128];
      }
      float pr[3];
      #pragma unroll
      for (int qq = 0; qq < 3; qq++)
        pr[qq] = s0 * w_sel[qq * (Hsz + Isz) + Hsz + k]
               + s1 * w_sel[qq * (Hsz + Isz) + Hsz + k + 128];
      #pragma unroll
      for (int off = 32; off; off >>= 1)
        #pragma unroll
        for (int qq = 0; qq < 3; qq++) pr[qq] += __shfl_xor(pr[qq], off);
      if (lane == 0) { red[wid][0]=pr[0]; red[wid][1]=pr[1]; red[wid][2]=pr[2]; }
    }
    __syncthreads();
    if (tid == 0) {
      #pragma unroll
      for (int qq = 0; qq < 3; qq++)
        xs[t * 3 + qq] = red[0][qq] + red[1][qq] + (float)Bsz * b_sel[qq];
    }
  }
}

// ---------------- fused: redundant select scan (per block, LDS) + gather ----------------
// score_h/xs written by the PREVIOUS launch -> visibility guaranteed by the
// launch boundary (no cooperative sync). Scan is deterministic -> all 2048
// blocks agree. Then grid-stride gather.
__global__ __launch_bounds__(256) void scan_gather(
    const _Float16* __restrict__ Hh,
    const float* __restrict__ score_h, const float* __restrict__ xs,
    float* __restrict__ out)
{
  __shared__ unsigned S[Tsz];
  const int tid = threadIdx.x;

  unsigned m = 0x24;                     // identity map: 0->0,1->1,2->2
  if (tid >= 1) {
    m = 0;
    const float* xr = xs + tid * 3;
    #pragma unroll
    for (int cc = 0; cc < 3; cc++) {
      const float* sh = score_h + ((size_t)cc * Tsz + (tid - 1)) * 3;
      const float v0 = sh[0] + xr[0];
      const float v1 = sh[1] + xr[1];
      const float v2 = sh[2] + xr[2];
      unsigned best = 0; float bv = v0;
      if (v1 > bv) { bv = v1; best = 1; }
      if (v2 > bv) { bv = v2; best = 2; }
      m |= best << (2 * cc);
    }
  }
  S[tid] = m;
  __syncthreads();

  #pragma unroll
  for (int dd = 1; dd < Tsz; dd <<= 1) {
    const unsigned prev = (tid >= dd) ? S[tid - dd] : 0x24u;  // identity pad
    const unsigned self = S[tid];
    __syncthreads();
    unsigned comp = 0;
    #pragma unroll
    for (int xx = 0; xx < 3; xx++) {
      const unsigned y = (prev >> (2 * xx)) & 3u;
      const unsigned z = (self >> (2 * y)) & 3u;
      comp |= z << (2 * xx);
    }
    S[tid] = comp;
    __syncthreads();
  }

  // ---- gather (grid-stride, 4 floats per iteration)
  const size_t BTH = (size_t)Bsz * Tsz * Hsz;
  const size_t N4 = (BTH + (size_t)Bsz * Hsz) / 4;
  for (size_t i4 = (size_t)blockIdx.x * 256 + tid; i4 < N4;
       i4 += (size_t)gridDim.x * 256) {
    const size_t idx = i4 * 4;
    int b, t, h;
    if (idx < BTH) {
      b = (int)(idx >> 16);
      const int rem = (int)(idx & 65535);
      t = rem >> 8; h = rem & 255;
    } else {
      const size_t r2 = idx - BTH;
      b = (int)(r2 >> 8); h = (int)(r2 & 255); t = Tsz - 1;
    }
    const int cc = (int)(S[t] & 3u);
    const size_t g = (((size_t)cc * Mrows + (size_t)b * Tsz + t) * Hsz + h);
    union { ushort4 u; _Float16 hv[4]; } cv;
    cv.u = *(const ushort4*)(Hh + g);
    float4 v;
    v.x = (float)cv.hv[0]; v.y = (float)cv.hv[1];
    v.z = (float)cv.hv[2]; v.w = (float)cv.hv[3];
    *(float4*)(out + idx) = v;
  }
}

extern "C" void kernel_launch(void* const* d_in, const int* in_sizes, int n_in,
                              void* d_out, int out_size, void* d_ws, size_t ws_size,
                              hipStream_t stream) {
  const float* x      = (const float*)d_in[0];
  const float* hidden = (const float*)d_in[1];
  const float* w_ih0  = (const float*)d_in[2];
  const float* b_ih0  = (const float*)d_in[3];
  const float* b_hh0  = (const float*)d_in[4];
  const float* w_ih   = (const float*)d_in[5];
  const float* b_ih   = (const float*)d_in[6];
  const float* b_hh   = (const float*)d_in[7];
  const float* w_lw   = (const float*)d_in[8];
  const float* b_lw   = (const float*)d_in[9];
  const float* w_sel  = (const float*)d_in[10];
  const float* b_sel  = (const float*)d_in[11];
  float* out = (float*)d_out;

  char* w = (char*)d_ws;
  const size_t HN = (size_t)3 * Mrows * 256;       // 25.2M
  const size_t XN = (size_t)Bsz * Tsz * Isz;       // 8.39M
  const size_t W0N = (size_t)3 * 768 * 256;        // 589824
  const size_t WLN = (size_t)3 * 3 * 768 * 256;    // 1769472
  _Float16* HA  = (_Float16*)w; w += HN * 2;
  _Float16* HB  = (_Float16*)w; w += HN * 2;
  _Float16* xh  = (_Float16*)w; w += XN * 2;
  _Float16* Wh0 = (_Float16*)w; w += W0N * 2;
  _Float16* WhL = (_Float16*)w; w += WLN * 2;
  float* e       = (float*)w; w += (size_t)3 * Tsz * Bsz * 16 * 4;
  float* p       = (float*)w; w += (size_t)3 * Tsz * Bsz * 12 * 4;
  float* score_h = (float*)w; w += (size_t)3 * Tsz * 3 * 4;
  float* xsb     = (float*)w; w += (size_t)Tsz * 3 * 4;

  // fp32 -> fp16 conversions (one launch, 3 segments)
  f32_to_f16_3<<<5248, 256, 0, stream>>>(
      x, xh, (int)(XN / 8),
      w_ih0, Wh0, (int)(W0N / 8),
      w_ih, WhL, (int)(WLN / 8));

  // layer 0: A = xh (shared across cur), gemm blocks only
  gemm_gru_f16<<<GEMM_BLOCKS, 256, 0, stream>>>(
      xh, (size_t)0, Wh0, (size_t)768 * 256,
      b_ih0, (size_t)768, b_hh0, (size_t)768, HA,
      nullptr, nullptr, nullptr, nullptr, -1);

  const size_t wcur = (size_t)3 * 768 * 256;
  const size_t bst  = (size_t)3 * 768;
  _Float16* ping = HA; _Float16* pong = HB;
  for (int l = 1; l < 4; l++) {
    // gemm(l) + tail-backfilled ep(l-1) over A = h_{l-1} (= ping)
    gemm_gru_f16<<<GEMM_BLOCKS + 1536, 256, 0, stream>>>(
        ping, (size_t)Mrows * 256,
        WhL + (size_t)(l - 1) * 768 * 256, wcur,
        b_ih + (size_t)(l - 1) * 768, bst,
        b_hh + (size_t)(l - 1) * 768, bst, pong,
        w_lw, w_sel, e, p, l - 1);
    _Float16* t1 = ping; ping = pong; pong = t1;
  }

  // layer-3 ep fused into attn (intra-block); xs in y==3 blocks
  attn_ep_xs<<<dim3(Tsz, 4), 256, 0, stream>>>(
      ping, e, p, hidden, b_lw, x, w_sel, b_sel, w_lw, score_h, xsb);

  // redundant per-block scan + gather (launch boundary guarantees visibility)
  scan_gather<<<2048, 256, 0, stream>>>(ping, score_h, xsb, out);
}